// Round 1
// baseline (1798.561 us; speedup 1.0000x reference)
//
#include <hip/hip_runtime.h>
#include <hip/hip_bf16.h>
#include <math.h>

// Problem constants (FusionDTI)
#define BATCH 32
#define LP 2048
#define LDRUG 512
#define DP 1280
#define DD 768
#define GP 256      // LP/8
#define GD 64       // LDRUG/8
#define HID 512
#define NH 8
#define HD 64
#define NKEY 320    // GP + GD concatenated keys
#define PST 328     // padded P row stride (f16) -> 2-way max bank conflict

typedef unsigned short ushort_t;
typedef __attribute__((ext_vector_type(8))) __bf16 bf16x8;
typedef __attribute__((ext_vector_type(8))) _Float16 f16x8;
typedef __attribute__((ext_vector_type(4))) float f32x4;

__device__ __forceinline__ ushort_t f2bf(float f) {
    unsigned int u = __float_as_uint(f);
    u += 0x7fff + ((u >> 16) & 1);          // round-to-nearest-even
    return (ushort_t)(u >> 16);
}

// ---------------------------------------------------------------------------
// Group mean -> bf16, vectorized float4 (4 d per thread)
// ---------------------------------------------------------------------------
__global__ void group_mean_kernel(const float* __restrict__ in,
                                  ushort_t* __restrict__ out, int D4, int total4) {
    int o = blockIdx.x * blockDim.x + threadIdx.x;
    if (o >= total4) return;
    int d = o % D4;
    long row = o / D4;
    const float4* p = (const float4*)in + row * 8 * (long)D4 + d;
    float4 s = {0.f, 0.f, 0.f, 0.f};
#pragma unroll
    for (int j = 0; j < 8; ++j) {
        float4 v = p[(long)j * D4];
        s.x += v.x; s.y += v.y; s.z += v.z; s.w += v.w;
    }
    uint2 r;
    r.x = (unsigned)f2bf(s.x * 0.125f) | ((unsigned)f2bf(s.y * 0.125f) << 16);
    r.y = (unsigned)f2bf(s.z * 0.125f) | ((unsigned)f2bf(s.w * 0.125f) << 16);
    *(uint2*)(out + (size_t)o * 4) = r;
}

__global__ void group_mask_kernel(const int* __restrict__ m,
                                  int* __restrict__ out, int total) {
    int o = blockIdx.x * blockDim.x + threadIdx.x;
    if (o >= total) return;
    const int* p = m + (long)o * 8;
    int any = 0;
#pragma unroll
    for (int j = 0; j < 8; ++j) any |= p[j];
    out[o] = any ? 1 : 0;
}

// ---------------------------------------------------------------------------
// Fused transpose+cast of all 8 weight matrices in ONE launch.
// ---------------------------------------------------------------------------
struct TransJobs {
    const float* src[8];
    ushort_t* dst[8];
    int K[8], N[8], base[8];   // base = first global tile index of job
};
__global__ __launch_bounds__(256) void transpose_cast8_kernel(TransJobs J) {
    __shared__ float tile[32][33];
    int tidx = blockIdx.x;
    int j = 0;
#pragma unroll
    for (int i = 1; i < 8; ++i) if (tidx >= J.base[i]) j = i;
    const float* W = J.src[j];
    ushort_t* Wt = J.dst[j];
    int K = J.K[j], N = J.N[j];
    int local = tidx - J.base[j];
    int kt = local % (K / 32), nt = local / (K / 32);
    int k0 = kt * 32, n0 = nt * 32;
    int tx = threadIdx.x & 31, ty = threadIdx.x >> 5;   // ty 0..7
#pragma unroll
    for (int i = 0; i < 32; i += 8)
        tile[ty + i][tx] = W[(size_t)(k0 + ty + i) * N + n0 + tx];
    __syncthreads();
#pragma unroll
    for (int i = 0; i < 32; i += 8)
        Wt[(size_t)(n0 + ty + i) * K + k0 + tx] = f2bf(tile[tx][ty + i]);
}

// ---------------------------------------------------------------------------
// MFMA bf16 GEMM (m97 structure): C = A @ Bt^T + bias, bf16 out.
// ---------------------------------------------------------------------------
__global__ __launch_bounds__(256) void mfma_gemm_kernel(
        const ushort_t* __restrict__ A, const ushort_t* __restrict__ Bt,
        const float* __restrict__ bias, ushort_t* __restrict__ C,
        int M, int N, int K) {
    __shared__ ushort_t As[128 * 32];
    __shared__ ushort_t Bs[128 * 32];
    const int t = threadIdx.x;
    const int m0 = blockIdx.y * 128, n0 = blockIdx.x * 128;
    const int wavebase = (t >> 6) * 64;
    const int lane = t & 63;
    const int lrow = lane & 15, quad = lane >> 4;
    const int m_base = ((t >> 6) >> 1) * 64;
    const int n_base = ((t >> 6) & 1) * 64;
    f32x4 acc[4][4] = {};

    for (int k0 = 0; k0 < K; k0 += 32) {
#pragma unroll
        for (int it = 0; it < 2; ++it) {
            int c = it * 256 + t;
            int row = c >> 2, kc = (c & 3) * 8;
            __builtin_amdgcn_global_load_lds(
                (const __attribute__((address_space(1))) void*)(A + (size_t)(m0 + row) * K + k0 + kc),
                (__attribute__((address_space(3))) void*)(As + (size_t)(it * 256 + wavebase) * 8),
                16, 0, 0);
            __builtin_amdgcn_global_load_lds(
                (const __attribute__((address_space(1))) void*)(Bt + (size_t)(n0 + row) * K + k0 + kc),
                (__attribute__((address_space(3))) void*)(Bs + (size_t)(it * 256 + wavebase) * 8),
                16, 0, 0);
        }
        __syncthreads();
        bf16x8 af[4], bfr[4];
#pragma unroll
        for (int i = 0; i < 4; ++i)
            af[i] = *(const bf16x8*)(As + (m_base + i * 16 + lrow) * 32 + quad * 8);
#pragma unroll
        for (int j = 0; j < 4; ++j)
            bfr[j] = *(const bf16x8*)(Bs + (n_base + j * 16 + lrow) * 32 + quad * 8);
#pragma unroll
        for (int i = 0; i < 4; ++i)
#pragma unroll
            for (int j = 0; j < 4; ++j)
                acc[i][j] = __builtin_amdgcn_mfma_f32_16x16x32_bf16(af[i], bfr[j], acc[i][j], 0, 0, 0);
        __syncthreads();
    }
#pragma unroll
    for (int i = 0; i < 4; ++i) {
#pragma unroll
        for (int j = 0; j < 4; ++j) {
            int n = n0 + n_base + j * 16 + lrow;
            float bv = bias ? bias[n] : 0.f;
#pragma unroll
            for (int r = 0; r < 4; ++r) {
                int m = m0 + m_base + i * 16 + quad * 4 + r;
                C[(size_t)m * N + n] = f2bf(acc[i][j][r] + bv);
            }
        }
    }
}

// ---------------------------------------------------------------------------
// QKV GEMM: A[M,512] bf16 @ Wt[1536,512]^T -> qkv fp16 [M][1536].
// Q,K columns (n<1024) stored to C; V columns only scattered into VT
// (C copy of V was never read -> skip it).
// ---------------------------------------------------------------------------
template<int G, int KEYOFF>
__global__ __launch_bounds__(256) void qkv_gemm_kernel(
        const ushort_t* __restrict__ A, const ushort_t* __restrict__ Bt,
        _Float16* __restrict__ C, _Float16* __restrict__ VT) {
    const int K = 512, N = 1536;
    __shared__ ushort_t As[128 * 32];
    __shared__ ushort_t Bs[128 * 32];
    const int t = threadIdx.x;
    const int m0 = blockIdx.y * 128, n0 = blockIdx.x * 128;
    const int wavebase = (t >> 6) * 64;
    const int lane = t & 63;
    const int lrow = lane & 15, quad = lane >> 4;
    const int m_base = ((t >> 6) >> 1) * 64;
    const int n_base = ((t >> 6) & 1) * 64;
    f32x4 acc[4][4] = {};

    for (int k0 = 0; k0 < K; k0 += 32) {
#pragma unroll
        for (int it = 0; it < 2; ++it) {
            int c = it * 256 + t;
            int row = c >> 2, kc = (c & 3) * 8;
            __builtin_amdgcn_global_load_lds(
                (const __attribute__((address_space(1))) void*)(A + (size_t)(m0 + row) * K + k0 + kc),
                (__attribute__((address_space(3))) void*)(As + (size_t)(it * 256 + wavebase) * 8),
                16, 0, 0);
            __builtin_amdgcn_global_load_lds(
                (const __attribute__((address_space(1))) void*)(Bt + (size_t)(n0 + row) * K + k0 + kc),
                (__attribute__((address_space(3))) void*)(Bs + (size_t)(it * 256 + wavebase) * 8),
                16, 0, 0);
        }
        __syncthreads();
        bf16x8 af[4], bfr[4];
#pragma unroll
        for (int i = 0; i < 4; ++i)
            af[i] = *(const bf16x8*)(As + (m_base + i * 16 + lrow) * 32 + quad * 8);
#pragma unroll
        for (int j = 0; j < 4; ++j)
            bfr[j] = *(const bf16x8*)(Bs + (n_base + j * 16 + lrow) * 32 + quad * 8);
#pragma unroll
        for (int i = 0; i < 4; ++i)
#pragma unroll
            for (int j = 0; j < 4; ++j)
                acc[i][j] = __builtin_amdgcn_mfma_f32_16x16x32_bf16(af[i], bfr[j], acc[i][j], 0, 0, 0);
        __syncthreads();
    }
#pragma unroll
    for (int i = 0; i < 4; ++i) {
#pragma unroll
        for (int j = 0; j < 4; ++j) {
            int n = n0 + n_base + j * 16 + lrow;
            int hh = (n - 1024) >> 6;       // head, valid when n >= 1024
            int dd = n & 63;
#pragma unroll
            for (int r = 0; r < 4; ++r) {
                int m = m0 + m_base + i * 16 + quad * 4 + r;
                _Float16 hv = (_Float16)acc[i][j][r];
                if (n < 1024) {
                    C[(size_t)m * N + n] = hv;
                } else {
                    int b = m / G, g = m % G;
                    VT[((size_t)(b * 8 + hh) * 64 + dd) * NKEY + KEYOFF + g] = hv;
                }
            }
        }
    }
}

// ---------------------------------------------------------------------------
// Fused attention: per (mtile, b*h) block computes 64 q-rows:
//   S = Q@K^T (f32, in-register) -> segmented masked softmax (in-register,
//   16-lane shfl reductions) -> P (f16, padded LDS) -> O = P@V -> column sums
//   atomically accumulated into x[B,1024] (masked-mean numerator).
// K staged swizzled in LDS ([key][64], 16B-col XOR row&7),
// V^T staged swizzled in LDS ([d][320], 16B-col XOR d&7).
// LDS total = 40960 + 40960 + 41984 + 1280 = 125184 B (1 block/CU).
// ---------------------------------------------------------------------------
__global__ __launch_bounds__(256) void fused_attn_kernel(
        const _Float16* __restrict__ qkvp, const _Float16* __restrict__ qkvd,
        const _Float16* __restrict__ VT,
        const int* __restrict__ mg, const int* __restrict__ md,
        float* __restrict__ x) {
    __shared__ _Float16 Ks[NKEY * 64];
    __shared__ _Float16 Vs[64 * NKEY];
    __shared__ _Float16 Ps[64 * PST];
    __shared__ int cm[NKEY];
    const int t = threadIdx.x;
    const int mtile = blockIdx.x, bh = blockIdx.y;
    const int b = bh >> 3, h = bh & 7;
    const int lane = t & 63, wid = t >> 6;
    const int lrow = lane & 15, quad = lane >> 4;

    if (t < GP) cm[t] = mg[b * GP + t];
    if (t < GD) cm[GP + t] = md[b * GD + t];

    // stage K rows (concat prot+drug keys), swizzled 16B columns
    for (int c = wid; c < 40; c += 4) {
        int row = c * 8 + (lane >> 3);
        int g16 = (lane & 7) ^ (row & 7);
        const _Float16* src = (row < GP)
            ? qkvp + ((size_t)(b * GP + row) * 1536 + 512 + h * HD) + g16 * 8
            : qkvd + ((size_t)(b * GD + row - GP) * 1536 + 512 + h * HD) + g16 * 8;
        __builtin_amdgcn_global_load_lds(
            (const __attribute__((address_space(1))) void*)src,
            (__attribute__((address_space(3))) void*)(Ks + (size_t)c * 512),
            16, 0, 0);
    }
    // stage V^T [d][key], swizzled 16B columns within 8-groups
    for (int c = wid; c < 40; c += 4) {
        int f = c * 64 + lane;
        int d = f / 40, c16 = f - d * 40;
        int gc = c16 ^ (d & 7);              // d&7 < 8: only low 3 bits flip
        const _Float16* src = VT + ((size_t)bh * 64 + d) * NKEY + gc * 8;
        __builtin_amdgcn_global_load_lds(
            (const __attribute__((address_space(1))) void*)src,
            (__attribute__((address_space(3))) void*)(Vs + (size_t)c * 512),
            16, 0, 0);
    }

    // Q fragments straight from global into registers
    const _Float16* Qb = (mtile < 4)
        ? qkvp + ((size_t)(b * GP + mtile * 64) * 1536 + h * HD)
        : qkvd + ((size_t)(b * GD) * 1536 + h * HD);
    const _Float16* qr = Qb + (size_t)(wid * 16 + lrow) * 1536 + quad * 8;
    f16x8 qf0 = *(const f16x8*)(qr);
    f16x8 qf1 = *(const f16x8*)(qr + 32);

    __syncthreads();

    // logits: sacc[nt] holds S[q = wid*16 + quad*4+r][key = nt*16 + lrow]
    f32x4 sacc[20] = {};
#pragma unroll
    for (int nt = 0; nt < 20; ++nt) {
        int key = nt * 16 + lrow;
        int x0 = (quad ^ (key & 7)) * 8;
        int x1 = ((4 + quad) ^ (key & 7)) * 8;
        f16x8 k0 = *(const f16x8*)(Ks + key * 64 + x0);
        f16x8 k1 = *(const f16x8*)(Ks + key * 64 + x1);
        sacc[nt] = __builtin_amdgcn_mfma_f32_16x16x32_f16(qf0, k0, sacc[nt], 0, 0, 0);
        sacc[nt] = __builtin_amdgcn_mfma_f32_16x16x32_f16(qf1, k1, sacc[nt], 0, 0, 0);
    }

    // segmented masked softmax, fully in registers
    int cmk[20];
#pragma unroll
    for (int nt = 0; nt < 20; ++nt) cmk[nt] = cm[nt * 16 + lrow];
    const int rbase = mtile * 64 + wid * 16 + quad * 4;
#pragma unroll
    for (int r = 0; r < 4; ++r) {
        int mrow = cm[rbase + r];
        float xv[20];
#pragma unroll
        for (int nt = 0; nt < 20; ++nt)
            xv[nt] = sacc[nt][r] - (cmk[nt] ? 0.f : 1e6f);
        // prot segment (keys 0..255 -> nt 0..15)
        float mx = xv[0];
#pragma unroll
        for (int nt = 1; nt < 16; ++nt) mx = fmaxf(mx, xv[nt]);
#pragma unroll
        for (int off = 1; off < 16; off <<= 1) mx = fmaxf(mx, __shfl_xor(mx, off));
        float e[20];
        float s = 0.f;
#pragma unroll
        for (int nt = 0; nt < 16; ++nt) { e[nt] = __expf(xv[nt] - mx); s += e[nt]; }
#pragma unroll
        for (int off = 1; off < 16; off <<= 1) s += __shfl_xor(s, off);
        float sp = mrow ? (1.f / s) : 0.f;
        // drug segment (keys 256..319 -> nt 16..19)
        float mx2 = fmaxf(fmaxf(xv[16], xv[17]), fmaxf(xv[18], xv[19]));
#pragma unroll
        for (int off = 1; off < 16; off <<= 1) mx2 = fmaxf(mx2, __shfl_xor(mx2, off));
        float s2 = 0.f;
#pragma unroll
        for (int nt = 16; nt < 20; ++nt) { e[nt] = __expf(xv[nt] - mx2); s2 += e[nt]; }
#pragma unroll
        for (int off = 1; off < 16; off <<= 1) s2 += __shfl_xor(s2, off);
        float sp2 = mrow ? (1.f / s2) : 0.f;
        int m = wid * 16 + quad * 4 + r;
#pragma unroll
        for (int nt = 0; nt < 16; ++nt)
            Ps[m * PST + nt * 16 + lrow] = (_Float16)(e[nt] * sp);
#pragma unroll
        for (int nt = 16; nt < 20; ++nt)
            Ps[m * PST + nt * 16 + lrow] = (_Float16)(e[nt] * sp2);
    }
    __syncthreads();

    // mix: O[q][d] = P[q][:] @ V[:][d]
    f32x4 oacc[4] = {};
#pragma unroll
    for (int kt = 0; kt < 10; ++kt) {
        f16x8 pa = *(const f16x8*)(Ps + (wid * 16 + lrow) * PST + kt * 32 + quad * 8);
#pragma unroll
        for (int nf = 0; nf < 4; ++nf) {
            int d = nf * 16 + lrow;
            int c16 = (kt * 4 + quad) ^ (d & 7);
            f16x8 vb = *(const f16x8*)(Vs + d * NKEY + c16 * 8);
            oacc[nf] = __builtin_amdgcn_mfma_f32_16x16x32_f16(pa, vb, oacc[nf], 0, 0, 0);
        }
    }

    // masked-mean numerator: column-sum the wave's 16 q-rows, atomically
    // accumulate *0.5 into x (prot rows -> x[:,0:512], drug -> x[:,512:1024])
    const int xoff = (mtile < 4) ? 0 : 512;
#pragma unroll
    for (int nf = 0; nf < 4; ++nf) {
        float cs = oacc[nf][0] + oacc[nf][1] + oacc[nf][2] + oacc[nf][3];
        cs += __shfl_xor(cs, 16);
        cs += __shfl_xor(cs, 32);
        if (quad == 0)
            atomicAdd(x + (size_t)b * 1024 + xoff + h * HD + nf * 16 + lrow, 0.5f * cs);
    }
}

__global__ void zero_x_kernel(float* __restrict__ x) {
    x[blockIdx.x * 256 + threadIdx.x] = 0.f;
}

// divide pooled sums by valid-group counts
__global__ void pool_div_kernel(float* __restrict__ x,
                                const int* __restrict__ mg, const int* __restrict__ md) {
    const int b = blockIdx.x, t = threadIdx.x;   // 1024 threads
    __shared__ float inv[2];
    if (t == 0) { int s = 0; for (int i = 0; i < GP; ++i) s += mg[b * GP + i] ? 1 : 0; inv[0] = 1.f / (float)s; }
    else if (t == 1) { int s = 0; for (int i = 0; i < GD; ++i) s += md[b * GD + i] ? 1 : 0; inv[1] = 1.f / (float)s; }
    __syncthreads();
    x[(size_t)b * 1024 + t] *= inv[t >> 9];
}

// ---------------------------------------------------------------------------
// Fused MLP layer: Y = BN(relu(X@W + b)) per 64-column block (all 32 rows).
// Biased variance over batch via E[x^2]-mu^2 (matches reference var(0)).
// ---------------------------------------------------------------------------
__global__ __launch_bounds__(256) void mlp_bn_kernel(
        const float* __restrict__ X, const float* __restrict__ W,
        const float* __restrict__ bias, const float* __restrict__ gamma,
        const float* __restrict__ beta, float* __restrict__ Y, int K, int N) {
    const int t = threadIdx.x;
    const int tc = t & 63, rg = t >> 6;          // col-in-block, row group (8 rows)
    const int c = blockIdx.x * 64 + tc;
    float acc[8] = {};
    const float* wc = W + c;
    const float* xr = X + (size_t)rg * 8 * K;
    for (int k = 0; k < K; ++k) {
        float w = wc[(size_t)k * N];
#pragma unroll
        for (int r = 0; r < 8; ++r)
            acc[r] = fmaf(xr[(size_t)r * K + k], w, acc[r]);
    }
    float bv = bias[c];
    float h[8], ps = 0.f, pq = 0.f;
#pragma unroll
    for (int r = 0; r < 8; ++r) {
        float v = fmaxf(acc[r] + bv, 0.f);
        h[r] = v; ps += v; pq += v * v;
    }
    __shared__ float red[2][4][64];
    red[0][rg][tc] = ps; red[1][rg][tc] = pq;
    __syncthreads();
    float mu  = (red[0][0][tc] + red[0][1][tc] + red[0][2][tc] + red[0][3][tc]) * (1.f / 32.f);
    float msq = (red[1][0][tc] + red[1][1][tc] + red[1][2][tc] + red[1][3][tc]) * (1.f / 32.f);
    float sc = gamma[c] * rsqrtf(msq - mu * mu + 1e-5f);
    float sh = beta[c] - mu * sc;
#pragma unroll
    for (int r = 0; r < 8; ++r)
        Y[(size_t)(rg * 8 + r) * N + c] = h[r] * sc + sh;
}

__global__ void final_kernel(const float* __restrict__ H, const float* __restrict__ wo,
                             const float* __restrict__ bo, float* __restrict__ out) {
    const int b = blockIdx.x, lane = threadIdx.x;   // 64 threads
    float p = 0.f;
#pragma unroll
    for (int j = 0; j < 4; ++j) {
        int idx = lane + j * 64;
        p += H[b * 256 + idx] * wo[idx];
    }
#pragma unroll
    for (int off = 32; off >= 1; off >>= 1) p += __shfl_xor(p, off);
    if (lane == 0) out[b] = 1.f / (1.f + expf(-(p + bo[0])));
}

// ---------------------------------------------------------------------------
extern "C" void kernel_launch(void* const* d_in, const int* in_sizes, int n_in,
                              void* d_out, int out_size, void* d_ws, size_t ws_size,
                              hipStream_t stream) {
    const float* prot_embed = (const float*)d_in[0];
    const float* drug_embed = (const float*)d_in[1];
    const int* prot_mask = (const int*)d_in[2];
    const int* drug_mask = (const int*)d_in[3];
    const float* w_preg = (const float*)d_in[4];
    const float* b_preg = (const float*)d_in[5];
    const float* w_dreg = (const float*)d_in[6];
    const float* b_dreg = (const float*)d_in[7];
    const float* wqp = (const float*)d_in[8];
    const float* wkp = (const float*)d_in[9];
    const float* wvp = (const float*)d_in[10];
    const float* wqd = (const float*)d_in[11];
    const float* wkd = (const float*)d_in[12];
    const float* wvd = (const float*)d_in[13];
    const float* w1 = (const float*)d_in[14];  const float* b1 = (const float*)d_in[15];
    const float* g1 = (const float*)d_in[16];  const float* be1 = (const float*)d_in[17];
    const float* w2 = (const float*)d_in[18];  const float* b2 = (const float*)d_in[19];
    const float* g2 = (const float*)d_in[20];  const float* be2 = (const float*)d_in[21];
    const float* w3 = (const float*)d_in[22];  const float* b3 = (const float*)d_in[23];
    const float* g3 = (const float*)d_in[24];  const float* be3 = (const float*)d_in[25];
    const float* wo = (const float*)d_in[26];  const float* bo = (const float*)d_in[27];

    // ---- workspace layout (elements) ----
    ushort_t* pgm = (ushort_t*)d_ws;                 // [8192][1280] bf16
    ushort_t* dgm = pgm + 10485760;                  // [2048][768] bf16
    ushort_t* wpreg_t = dgm + 1572864;               // [512][1280]
    ushort_t* wdreg_t = wpreg_t + 655360;            // [512][768]
    ushort_t* wqkvp_t = wdreg_t + 393216;            // [1536][512]
    ushort_t* wqkvd_t = wqkvp_t + 786432;            // [1536][512]
    ushort_t* pg = wqkvd_t + 786432;                 // [8192][512] bf16
    ushort_t* dg = pg + 4194304;                     // [2048][512] bf16
    _Float16* qkvp = (_Float16*)(dg + 1048576);      // [8192][1536] f16
    _Float16* qkvd = qkvp + 12582912;                // [2048][1536] f16
    _Float16* VT   = qkvd + 3145728;                 // [256][64][320] f16
    int* mg = (int*)(VT + 5242880);                  // [8192]
    int* md = mg + 8192;                             // [2048]
    // overlay: dgm dead after drug regression GEMM -> x / MLP tmps
    float* x  = (float*)dgm;                         // [32][1024]
    float* h1 = x + 32768;
    float* h2 = h1 + 32768;
    float* h3 = h2 + 16384;

    // 1. group means (mean commutes with the linear regression layers) -> bf16
    group_mean_kernel<<<(BATCH * GP * DP / 4) / 256, 256, 0, stream>>>(prot_embed, pgm, DP / 4, BATCH * GP * DP / 4);
    group_mean_kernel<<<(BATCH * GD * DD / 4) / 256, 256, 0, stream>>>(drug_embed, dgm, DD / 4, BATCH * GD * DD / 4);
    group_mask_kernel<<<(BATCH * GP) / 256, 256, 0, stream>>>(prot_mask, mg, BATCH * GP);
    group_mask_kernel<<<(BATCH * GD) / 256, 256, 0, stream>>>(drug_mask, md, BATCH * GD);

    // 2. all 8 weight transposes in one launch
    TransJobs J;
    J.src[0] = w_preg; J.dst[0] = wpreg_t; J.K[0] = DP;  J.N[0] = HID;
    J.src[1] = w_dreg; J.dst[1] = wdreg_t; J.K[1] = DD;  J.N[1] = HID;
    J.src[2] = wqp; J.dst[2] = wqkvp_t;              J.K[2] = HID; J.N[2] = HID;
    J.src[3] = wkp; J.dst[3] = wqkvp_t + 512 * 512;  J.K[3] = HID; J.N[3] = HID;
    J.src[4] = wvp; J.dst[4] = wqkvp_t + 1024 * 512; J.K[4] = HID; J.N[4] = HID;
    J.src[5] = wqd; J.dst[5] = wqkvd_t;              J.K[5] = HID; J.N[5] = HID;
    J.src[6] = wkd; J.dst[6] = wqkvd_t + 512 * 512;  J.K[6] = HID; J.N[6] = HID;
    J.src[7] = wvd; J.dst[7] = wqkvd_t + 1024 * 512; J.K[7] = HID; J.N[7] = HID;
    {
        int base = 0;
        for (int i = 0; i < 8; ++i) { J.base[i] = base; base += (J.K[i] / 32) * (J.N[i] / 32); }
        transpose_cast8_kernel<<<base, 256, 0, stream>>>(J);
    }

    // 3. regression GEMMs (bf16 out, bias), then fused QKV GEMMs (f16 out + VT)
    mfma_gemm_kernel<<<dim3(HID / 128, (BATCH * GP) / 128), 256, 0, stream>>>(
        pgm, wpreg_t, b_preg, pg, BATCH * GP, HID, DP);
    mfma_gemm_kernel<<<dim3(HID / 128, (BATCH * GD) / 128), 256, 0, stream>>>(
        dgm, wdreg_t, b_dreg, dg, BATCH * GD, HID, DD);
    // dgm now dead -> zero the pooled-x accumulator (overlays dgm)
    zero_x_kernel<<<128, 256, 0, stream>>>(x);
    qkv_gemm_kernel<GP, 0><<<dim3(1536 / 128, (BATCH * GP) / 128), 256, 0, stream>>>(
        pg, wqkvp_t, qkvp, VT);
    qkv_gemm_kernel<GD, GP><<<dim3(1536 / 128, (BATCH * GD) / 128), 256, 0, stream>>>(
        dg, wqkvd_t, qkvd, VT);

    // 4. fused attention (logits + segmented masked softmax + mix + pooled sums)
    fused_attn_kernel<<<dim3(5, BATCH * NH), 256, 0, stream>>>(qkvp, qkvd, VT, mg, md, x);

    // 5. masked-mean: divide pooled sums by counts
    pool_div_kernel<<<BATCH, 1024, 0, stream>>>(x, mg, md);

    // 6. MLP head (gemm+relu+BN fused per layer)
    mlp_bn_kernel<<<1024 / 64, 256, 0, stream>>>(x, w1, b1, g1, be1, h1, 1024, 1024);
    mlp_bn_kernel<<<512 / 64, 256, 0, stream>>>(h1, w2, b2, g2, be2, h2, 1024, 512);
    mlp_bn_kernel<<<256 / 64, 256, 0, stream>>>(h2, w3, b3, g3, be3, h3, 512, 256);
    final_kernel<<<BATCH, 64, 0, stream>>>(h3, wo, bo, (float*)d_out);
}

// Round 2
// 872.026 us; speedup vs baseline: 2.0625x; 2.0625x over previous
//
#include <hip/hip_runtime.h>
#include <hip/hip_bf16.h>
#include <math.h>

// Problem constants (FusionDTI)
#define BATCH 32
#define LP 2048
#define LDRUG 512
#define DP 1280
#define DD 768
#define GP 256      // LP/8
#define GD 64       // LDRUG/8
#define HID 512
#define NH 8
#define HD 64
#define NKEY 320    // GP + GD concatenated keys
#define PST 328     // padded P row stride (f16) -> 2-way max bank conflict

typedef unsigned short ushort_t;
typedef __attribute__((ext_vector_type(8))) __bf16 bf16x8;
typedef __attribute__((ext_vector_type(8))) _Float16 f16x8;
typedef __attribute__((ext_vector_type(4))) float f32x4;

__device__ __forceinline__ ushort_t f2bf(float f) {
    unsigned int u = __float_as_uint(f);
    u += 0x7fff + ((u >> 16) & 1);          // round-to-nearest-even
    return (ushort_t)(u >> 16);
}

// ---------------------------------------------------------------------------
// Group mean -> bf16, vectorized float4 (4 d per thread)
// ---------------------------------------------------------------------------
__global__ void group_mean_kernel(const float* __restrict__ in,
                                  ushort_t* __restrict__ out, int D4, int total4) {
    int o = blockIdx.x * blockDim.x + threadIdx.x;
    if (o >= total4) return;
    int d = o % D4;
    long row = o / D4;
    const float4* p = (const float4*)in + row * 8 * (long)D4 + d;
    float4 s = {0.f, 0.f, 0.f, 0.f};
#pragma unroll
    for (int j = 0; j < 8; ++j) {
        float4 v = p[(long)j * D4];
        s.x += v.x; s.y += v.y; s.z += v.z; s.w += v.w;
    }
    uint2 r;
    r.x = (unsigned)f2bf(s.x * 0.125f) | ((unsigned)f2bf(s.y * 0.125f) << 16);
    r.y = (unsigned)f2bf(s.z * 0.125f) | ((unsigned)f2bf(s.w * 0.125f) << 16);
    *(uint2*)(out + (size_t)o * 4) = r;
}

__global__ void group_mask_kernel(const int* __restrict__ m,
                                  int* __restrict__ out, int total) {
    int o = blockIdx.x * blockDim.x + threadIdx.x;
    if (o >= total) return;
    const int* p = m + (long)o * 8;
    int any = 0;
#pragma unroll
    for (int j = 0; j < 8; ++j) any |= p[j];
    out[o] = any ? 1 : 0;
}

// ---------------------------------------------------------------------------
// Fused transpose+cast of all 8 weight matrices in ONE launch.
// ---------------------------------------------------------------------------
struct TransJobs {
    const float* src[8];
    ushort_t* dst[8];
    int K[8], N[8], base[8];   // base = first global tile index of job
};
__global__ __launch_bounds__(256) void transpose_cast8_kernel(TransJobs J) {
    __shared__ float tile[32][33];
    int tidx = blockIdx.x;
    int j = 0;
#pragma unroll
    for (int i = 1; i < 8; ++i) if (tidx >= J.base[i]) j = i;
    const float* W = J.src[j];
    ushort_t* Wt = J.dst[j];
    int K = J.K[j], N = J.N[j];
    int local = tidx - J.base[j];
    int kt = local % (K / 32), nt = local / (K / 32);
    int k0 = kt * 32, n0 = nt * 32;
    int tx = threadIdx.x & 31, ty = threadIdx.x >> 5;   // ty 0..7
#pragma unroll
    for (int i = 0; i < 32; i += 8)
        tile[ty + i][tx] = W[(size_t)(k0 + ty + i) * N + n0 + tx];
    __syncthreads();
#pragma unroll
    for (int i = 0; i < 32; i += 8)
        Wt[(size_t)(n0 + ty + i) * K + k0 + tx] = f2bf(tile[tx][ty + i]);
}

// ---------------------------------------------------------------------------
// MFMA bf16 GEMM (m97 structure): C = A @ Bt^T + bias, bf16 out.
// ---------------------------------------------------------------------------
__global__ __launch_bounds__(256) void mfma_gemm_kernel(
        const ushort_t* __restrict__ A, const ushort_t* __restrict__ Bt,
        const float* __restrict__ bias, ushort_t* __restrict__ C,
        int M, int N, int K) {
    __shared__ ushort_t As[128 * 32];
    __shared__ ushort_t Bs[128 * 32];
    const int t = threadIdx.x;
    const int m0 = blockIdx.y * 128, n0 = blockIdx.x * 128;
    const int wavebase = (t >> 6) * 64;
    const int lane = t & 63;
    const int lrow = lane & 15, quad = lane >> 4;
    const int m_base = ((t >> 6) >> 1) * 64;
    const int n_base = ((t >> 6) & 1) * 64;
    f32x4 acc[4][4] = {};

    for (int k0 = 0; k0 < K; k0 += 32) {
#pragma unroll
        for (int it = 0; it < 2; ++it) {
            int c = it * 256 + t;
            int row = c >> 2, kc = (c & 3) * 8;
            __builtin_amdgcn_global_load_lds(
                (const __attribute__((address_space(1))) void*)(A + (size_t)(m0 + row) * K + k0 + kc),
                (__attribute__((address_space(3))) void*)(As + (size_t)(it * 256 + wavebase) * 8),
                16, 0, 0);
            __builtin_amdgcn_global_load_lds(
                (const __attribute__((address_space(1))) void*)(Bt + (size_t)(n0 + row) * K + k0 + kc),
                (__attribute__((address_space(3))) void*)(Bs + (size_t)(it * 256 + wavebase) * 8),
                16, 0, 0);
        }
        __syncthreads();
        bf16x8 af[4], bfr[4];
#pragma unroll
        for (int i = 0; i < 4; ++i)
            af[i] = *(const bf16x8*)(As + (m_base + i * 16 + lrow) * 32 + quad * 8);
#pragma unroll
        for (int j = 0; j < 4; ++j)
            bfr[j] = *(const bf16x8*)(Bs + (n_base + j * 16 + lrow) * 32 + quad * 8);
#pragma unroll
        for (int i = 0; i < 4; ++i)
#pragma unroll
            for (int j = 0; j < 4; ++j)
                acc[i][j] = __builtin_amdgcn_mfma_f32_16x16x32_bf16(af[i], bfr[j], acc[i][j], 0, 0, 0);
        __syncthreads();
    }
#pragma unroll
    for (int i = 0; i < 4; ++i) {
#pragma unroll
        for (int j = 0; j < 4; ++j) {
            int n = n0 + n_base + j * 16 + lrow;
            float bv = bias ? bias[n] : 0.f;
#pragma unroll
            for (int r = 0; r < 4; ++r) {
                int m = m0 + m_base + i * 16 + quad * 4 + r;
                C[(size_t)m * N + n] = f2bf(acc[i][j][r] + bv);
            }
        }
    }
}

// ---------------------------------------------------------------------------
// QKV GEMM: A[M,512] bf16 @ Wt[1536,512]^T -> qkv fp16 [M][1536].
// Q,K columns (n<1024) stored to C; V columns only scattered into VT
// (C copy of V was never read -> skip it).
// ---------------------------------------------------------------------------
template<int G, int KEYOFF>
__global__ __launch_bounds__(256) void qkv_gemm_kernel(
        const ushort_t* __restrict__ A, const ushort_t* __restrict__ Bt,
        _Float16* __restrict__ C, _Float16* __restrict__ VT) {
    const int K = 512, N = 1536;
    __shared__ ushort_t As[128 * 32];
    __shared__ ushort_t Bs[128 * 32];
    const int t = threadIdx.x;
    const int m0 = blockIdx.y * 128, n0 = blockIdx.x * 128;
    const int wavebase = (t >> 6) * 64;
    const int lane = t & 63;
    const int lrow = lane & 15, quad = lane >> 4;
    const int m_base = ((t >> 6) >> 1) * 64;
    const int n_base = ((t >> 6) & 1) * 64;
    f32x4 acc[4][4] = {};

    for (int k0 = 0; k0 < K; k0 += 32) {
#pragma unroll
        for (int it = 0; it < 2; ++it) {
            int c = it * 256 + t;
            int row = c >> 2, kc = (c & 3) * 8;
            __builtin_amdgcn_global_load_lds(
                (const __attribute__((address_space(1))) void*)(A + (size_t)(m0 + row) * K + k0 + kc),
                (__attribute__((address_space(3))) void*)(As + (size_t)(it * 256 + wavebase) * 8),
                16, 0, 0);
            __builtin_amdgcn_global_load_lds(
                (const __attribute__((address_space(1))) void*)(Bt + (size_t)(n0 + row) * K + k0 + kc),
                (__attribute__((address_space(3))) void*)(Bs + (size_t)(it * 256 + wavebase) * 8),
                16, 0, 0);
        }
        __syncthreads();
        bf16x8 af[4], bfr[4];
#pragma unroll
        for (int i = 0; i < 4; ++i)
            af[i] = *(const bf16x8*)(As + (m_base + i * 16 + lrow) * 32 + quad * 8);
#pragma unroll
        for (int j = 0; j < 4; ++j)
            bfr[j] = *(const bf16x8*)(Bs + (n_base + j * 16 + lrow) * 32 + quad * 8);
#pragma unroll
        for (int i = 0; i < 4; ++i)
#pragma unroll
            for (int j = 0; j < 4; ++j)
                acc[i][j] = __builtin_amdgcn_mfma_f32_16x16x32_bf16(af[i], bfr[j], acc[i][j], 0, 0, 0);
        __syncthreads();
    }
#pragma unroll
    for (int i = 0; i < 4; ++i) {
#pragma unroll
        for (int j = 0; j < 4; ++j) {
            int n = n0 + n_base + j * 16 + lrow;
            int hh = (n - 1024) >> 6;       // head, valid when n >= 1024
            int dd = n & 63;
#pragma unroll
            for (int r = 0; r < 4; ++r) {
                int m = m0 + m_base + i * 16 + quad * 4 + r;
                _Float16 hv = (_Float16)acc[i][j][r];
                if (n < 1024) {
                    C[(size_t)m * N + n] = hv;
                } else {
                    int b = m / G, g = m % G;
                    VT[((size_t)(b * 8 + hh) * 64 + dd) * NKEY + KEYOFF + g] = hv;
                }
            }
        }
    }
}

// ---------------------------------------------------------------------------
// Fused attention: per (mtile, b*h) block computes 64 q-rows:
//   S = Q@K^T (f32, in-register) -> segmented masked softmax (in-register,
//   16-lane shfl reductions) -> P (f16, padded LDS) -> O = P@V -> column sums
//   atomically accumulated into x[B,1024] (masked-mean numerator).
// ---------------------------------------------------------------------------
__global__ __launch_bounds__(256) void fused_attn_kernel(
        const _Float16* __restrict__ qkvp, const _Float16* __restrict__ qkvd,
        const _Float16* __restrict__ VT,
        const int* __restrict__ mg, const int* __restrict__ md,
        float* __restrict__ x) {
    __shared__ _Float16 Ks[NKEY * 64];
    __shared__ _Float16 Vs[64 * NKEY];
    __shared__ _Float16 Ps[64 * PST];
    __shared__ int cm[NKEY];
    const int t = threadIdx.x;
    const int mtile = blockIdx.x, bh = blockIdx.y;
    const int b = bh >> 3, h = bh & 7;
    const int lane = t & 63, wid = t >> 6;
    const int lrow = lane & 15, quad = lane >> 4;

    if (t < GP) cm[t] = mg[b * GP + t];
    if (t < GD) cm[GP + t] = md[b * GD + t];

    // stage K rows (concat prot+drug keys), swizzled 16B columns
    for (int c = wid; c < 40; c += 4) {
        int row = c * 8 + (lane >> 3);
        int g16 = (lane & 7) ^ (row & 7);
        const _Float16* src = (row < GP)
            ? qkvp + ((size_t)(b * GP + row) * 1536 + 512 + h * HD) + g16 * 8
            : qkvd + ((size_t)(b * GD + row - GP) * 1536 + 512 + h * HD) + g16 * 8;
        __builtin_amdgcn_global_load_lds(
            (const __attribute__((address_space(1))) void*)src,
            (__attribute__((address_space(3))) void*)(Ks + (size_t)c * 512),
            16, 0, 0);
    }
    // stage V^T [d][key], swizzled 16B columns within 8-groups
    for (int c = wid; c < 40; c += 4) {
        int f = c * 64 + lane;
        int d = f / 40, c16 = f - d * 40;
        int gc = c16 ^ (d & 7);              // d&7 < 8: only low 3 bits flip
        const _Float16* src = VT + ((size_t)bh * 64 + d) * NKEY + gc * 8;
        __builtin_amdgcn_global_load_lds(
            (const __attribute__((address_space(1))) void*)src,
            (__attribute__((address_space(3))) void*)(Vs + (size_t)c * 512),
            16, 0, 0);
    }

    // Q fragments straight from global into registers
    const _Float16* Qb = (mtile < 4)
        ? qkvp + ((size_t)(b * GP + mtile * 64) * 1536 + h * HD)
        : qkvd + ((size_t)(b * GD) * 1536 + h * HD);
    const _Float16* qr = Qb + (size_t)(wid * 16 + lrow) * 1536 + quad * 8;
    f16x8 qf0 = *(const f16x8*)(qr);
    f16x8 qf1 = *(const f16x8*)(qr + 32);

    __syncthreads();

    // logits: sacc[nt] holds S[q = wid*16 + quad*4+r][key = nt*16 + lrow]
    f32x4 sacc[20] = {};
#pragma unroll
    for (int nt = 0; nt < 20; ++nt) {
        int key = nt * 16 + lrow;
        int x0 = (quad ^ (key & 7)) * 8;
        int x1 = ((4 + quad) ^ (key & 7)) * 8;
        f16x8 k0 = *(const f16x8*)(Ks + key * 64 + x0);
        f16x8 k1 = *(const f16x8*)(Ks + key * 64 + x1);
        sacc[nt] = __builtin_amdgcn_mfma_f32_16x16x32_f16(qf0, k0, sacc[nt], 0, 0, 0);
        sacc[nt] = __builtin_amdgcn_mfma_f32_16x16x32_f16(qf1, k1, sacc[nt], 0, 0, 0);
    }

    // segmented masked softmax, fully in registers
    int cmk[20];
#pragma unroll
    for (int nt = 0; nt < 20; ++nt) cmk[nt] = cm[nt * 16 + lrow];
    const int rbase = mtile * 64 + wid * 16 + quad * 4;
#pragma unroll
    for (int r = 0; r < 4; ++r) {
        int mrow = cm[rbase + r];
        float xv[20];
#pragma unroll
        for (int nt = 0; nt < 20; ++nt)
            xv[nt] = sacc[nt][r] - (cmk[nt] ? 0.f : 1e6f);
        // prot segment (keys 0..255 -> nt 0..15)
        float mx = xv[0];
#pragma unroll
        for (int nt = 1; nt < 16; ++nt) mx = fmaxf(mx, xv[nt]);
#pragma unroll
        for (int off = 1; off < 16; off <<= 1) mx = fmaxf(mx, __shfl_xor(mx, off));
        float e[20];
        float s = 0.f;
#pragma unroll
        for (int nt = 0; nt < 16; ++nt) { e[nt] = __expf(xv[nt] - mx); s += e[nt]; }
#pragma unroll
        for (int off = 1; off < 16; off <<= 1) s += __shfl_xor(s, off);
        float sp = mrow ? (1.f / s) : 0.f;
        // drug segment (keys 256..319 -> nt 16..19)
        float mx2 = fmaxf(fmaxf(xv[16], xv[17]), fmaxf(xv[18], xv[19]));
#pragma unroll
        for (int off = 1; off < 16; off <<= 1) mx2 = fmaxf(mx2, __shfl_xor(mx2, off));
        float s2 = 0.f;
#pragma unroll
        for (int nt = 16; nt < 20; ++nt) { e[nt] = __expf(xv[nt] - mx2); s2 += e[nt]; }
#pragma unroll
        for (int off = 1; off < 16; off <<= 1) s2 += __shfl_xor(s2, off);
        float sp2 = mrow ? (1.f / s2) : 0.f;
        int m = wid * 16 + quad * 4 + r;
#pragma unroll
        for (int nt = 0; nt < 16; ++nt)
            Ps[m * PST + nt * 16 + lrow] = (_Float16)(e[nt] * sp);
#pragma unroll
        for (int nt = 16; nt < 20; ++nt)
            Ps[m * PST + nt * 16 + lrow] = (_Float16)(e[nt] * sp2);
    }
    __syncthreads();

    // mix: O[q][d] = P[q][:] @ V[:][d]
    f32x4 oacc[4] = {};
#pragma unroll
    for (int kt = 0; kt < 10; ++kt) {
        f16x8 pa = *(const f16x8*)(Ps + (wid * 16 + lrow) * PST + kt * 32 + quad * 8);
#pragma unroll
        for (int nf = 0; nf < 4; ++nf) {
            int d = nf * 16 + lrow;
            int c16 = (kt * 4 + quad) ^ (d & 7);
            f16x8 vb = *(const f16x8*)(Vs + d * NKEY + c16 * 8);
            oacc[nf] = __builtin_amdgcn_mfma_f32_16x16x32_f16(pa, vb, oacc[nf], 0, 0, 0);
        }
    }

    // masked-mean numerator: column-sum the wave's 16 q-rows, atomically
    // accumulate *0.5 into x (prot rows -> x[:,0:512], drug -> x[:,512:1024])
    const int xoff = (mtile < 4) ? 0 : 512;
#pragma unroll
    for (int nf = 0; nf < 4; ++nf) {
        float cs = oacc[nf][0] + oacc[nf][1] + oacc[nf][2] + oacc[nf][3];
        cs += __shfl_xor(cs, 16);
        cs += __shfl_xor(cs, 32);
        if (quad == 0)
            atomicAdd(x + (size_t)b * 1024 + xoff + h * HD + nf * 16 + lrow, 0.5f * cs);
    }
}

__global__ void zero_x_kernel(float* __restrict__ x) {
    x[blockIdx.x * 256 + threadIdx.x] = 0.f;
}

// divide pooled sums by valid-group counts
__global__ void pool_div_kernel(float* __restrict__ x,
                                const int* __restrict__ mg, const int* __restrict__ md) {
    const int b = blockIdx.x, t = threadIdx.x;   // 1024 threads
    __shared__ float inv[2];
    if (t == 0) { int s = 0; for (int i = 0; i < GP; ++i) s += mg[b * GP + i] ? 1 : 0; inv[0] = 1.f / (float)s; }
    else if (t == 1) { int s = 0; for (int i = 0; i < GD; ++i) s += md[b * GD + i] ? 1 : 0; inv[1] = 1.f / (float)s; }
    __syncthreads();
    x[(size_t)b * 1024 + t] *= inv[t >> 9];
}

// ---------------------------------------------------------------------------
// Tiny-M (32) MLP GEMM (fp32): thread per output element, 128/64/32-block
// grids give enough TLP that the K-loop's W loads pipeline (L2-hit after the
// first m-row reads a line). unroll 8 -> 16 independent loads in flight.
// ---------------------------------------------------------------------------
__global__ void mlp_gemm_kernel(const float* __restrict__ X, const float* __restrict__ W,
                                const float* __restrict__ bias, float* __restrict__ Y,
                                int K, int N, int do_relu) {
    int g = blockIdx.x * blockDim.x + threadIdx.x;
    int m = g / N, n = g % N;
    float acc = bias[n];
    const float* xr = X + (size_t)m * K;
    const float* wc = W + n;
#pragma unroll 8
    for (int k = 0; k < K; ++k) acc += xr[k] * wc[(size_t)k * N];
    if (do_relu) acc = fmaxf(acc, 0.f);
    Y[g] = acc;
}

__global__ void bn_kernel(float* __restrict__ Y, const float* __restrict__ gamma,
                          const float* __restrict__ beta, int F) {
    int f = blockIdx.x * blockDim.x + threadIdx.x;
    if (f >= F) return;
    float mu = 0.f;
    for (int r = 0; r < BATCH; ++r) mu += Y[(size_t)r * F + f];
    mu *= (1.f / BATCH);
    float var = 0.f;
    for (int r = 0; r < BATCH; ++r) {
        float d = Y[(size_t)r * F + f] - mu;
        var += d * d;
    }
    var *= (1.f / BATCH);
    float sc = gamma[f] * rsqrtf(var + 1e-5f);
    float bb = beta[f];
    for (int r = 0; r < BATCH; ++r)
        Y[(size_t)r * F + f] = (Y[(size_t)r * F + f] - mu) * sc + bb;
}

__global__ void final_kernel(const float* __restrict__ H, const float* __restrict__ wo,
                             const float* __restrict__ bo, float* __restrict__ out) {
    const int b = blockIdx.x, lane = threadIdx.x;   // 64 threads
    float p = 0.f;
#pragma unroll
    for (int j = 0; j < 4; ++j) {
        int idx = lane + j * 64;
        p += H[b * 256 + idx] * wo[idx];
    }
#pragma unroll
    for (int off = 32; off >= 1; off >>= 1) p += __shfl_xor(p, off);
    if (lane == 0) out[b] = 1.f / (1.f + expf(-(p + bo[0])));
}

// ---------------------------------------------------------------------------
extern "C" void kernel_launch(void* const* d_in, const int* in_sizes, int n_in,
                              void* d_out, int out_size, void* d_ws, size_t ws_size,
                              hipStream_t stream) {
    const float* prot_embed = (const float*)d_in[0];
    const float* drug_embed = (const float*)d_in[1];
    const int* prot_mask = (const int*)d_in[2];
    const int* drug_mask = (const int*)d_in[3];
    const float* w_preg = (const float*)d_in[4];
    const float* b_preg = (const float*)d_in[5];
    const float* w_dreg = (const float*)d_in[6];
    const float* b_dreg = (const float*)d_in[7];
    const float* wqp = (const float*)d_in[8];
    const float* wkp = (const float*)d_in[9];
    const float* wvp = (const float*)d_in[10];
    const float* wqd = (const float*)d_in[11];
    const float* wkd = (const float*)d_in[12];
    const float* wvd = (const float*)d_in[13];
    const float* w1 = (const float*)d_in[14];  const float* b1 = (const float*)d_in[15];
    const float* g1 = (const float*)d_in[16];  const float* be1 = (const float*)d_in[17];
    const float* w2 = (const float*)d_in[18];  const float* b2 = (const float*)d_in[19];
    const float* g2 = (const float*)d_in[20];  const float* be2 = (const float*)d_in[21];
    const float* w3 = (const float*)d_in[22];  const float* b3 = (const float*)d_in[23];
    const float* g3 = (const float*)d_in[24];  const float* be3 = (const float*)d_in[25];
    const float* wo = (const float*)d_in[26];  const float* bo = (const float*)d_in[27];

    // ---- workspace layout (elements) ----
    ushort_t* pgm = (ushort_t*)d_ws;                 // [8192][1280] bf16
    ushort_t* dgm = pgm + 10485760;                  // [2048][768] bf16
    ushort_t* wpreg_t = dgm + 1572864;               // [512][1280]
    ushort_t* wdreg_t = wpreg_t + 655360;            // [512][768]
    ushort_t* wqkvp_t = wdreg_t + 393216;            // [1536][512]
    ushort_t* wqkvd_t = wqkvp_t + 786432;            // [1536][512]
    ushort_t* pg = wqkvd_t + 786432;                 // [8192][512] bf16
    ushort_t* dg = pg + 4194304;                     // [2048][512] bf16
    _Float16* qkvp = (_Float16*)(dg + 1048576);      // [8192][1536] f16
    _Float16* qkvd = qkvp + 12582912;                // [2048][1536] f16
    _Float16* VT   = qkvd + 3145728;                 // [256][64][320] f16
    int* mg = (int*)(VT + 5242880);                  // [8192]
    int* md = mg + 8192;                             // [2048]
    // overlay: dgm dead after drug regression GEMM -> x / MLP tmps
    float* x  = (float*)dgm;                         // [32][1024]
    float* h1 = x + 32768;
    float* h2 = h1 + 32768;
    float* h3 = h2 + 16384;

    // 1. group means (mean commutes with the linear regression layers) -> bf16
    group_mean_kernel<<<(BATCH * GP * DP / 4) / 256, 256, 0, stream>>>(prot_embed, pgm, DP / 4, BATCH * GP * DP / 4);
    group_mean_kernel<<<(BATCH * GD * DD / 4) / 256, 256, 0, stream>>>(drug_embed, dgm, DD / 4, BATCH * GD * DD / 4);
    group_mask_kernel<<<(BATCH * GP) / 256, 256, 0, stream>>>(prot_mask, mg, BATCH * GP);
    group_mask_kernel<<<(BATCH * GD) / 256, 256, 0, stream>>>(drug_mask, md, BATCH * GD);

    // 2. all 8 weight transposes in one launch
    TransJobs J;
    J.src[0] = w_preg; J.dst[0] = wpreg_t; J.K[0] = DP;  J.N[0] = HID;
    J.src[1] = w_dreg; J.dst[1] = wdreg_t; J.K[1] = DD;  J.N[1] = HID;
    J.src[2] = wqp; J.dst[2] = wqkvp_t;              J.K[2] = HID; J.N[2] = HID;
    J.src[3] = wkp; J.dst[3] = wqkvp_t + 512 * 512;  J.K[3] = HID; J.N[3] = HID;
    J.src[4] = wvp; J.dst[4] = wqkvp_t + 1024 * 512; J.K[4] = HID; J.N[4] = HID;
    J.src[5] = wqd; J.dst[5] = wqkvd_t;              J.K[5] = HID; J.N[5] = HID;
    J.src[6] = wkd; J.dst[6] = wqkvd_t + 512 * 512;  J.K[6] = HID; J.N[6] = HID;
    J.src[7] = wvd; J.dst[7] = wqkvd_t + 1024 * 512; J.K[7] = HID; J.N[7] = HID;
    {
        int base = 0;
        for (int i = 0; i < 8; ++i) { J.base[i] = base; base += (J.K[i] / 32) * (J.N[i] / 32); }
        transpose_cast8_kernel<<<base, 256, 0, stream>>>(J);
    }

    // 3. regression GEMMs (bf16 out, bias), then fused QKV GEMMs (f16 out + VT)
    mfma_gemm_kernel<<<dim3(HID / 128, (BATCH * GP) / 128), 256, 0, stream>>>(
        pgm, wpreg_t, b_preg, pg, BATCH * GP, HID, DP);
    mfma_gemm_kernel<<<dim3(HID / 128, (BATCH * GD) / 128), 256, 0, stream>>>(
        dgm, wdreg_t, b_dreg, dg, BATCH * GD, HID, DD);
    // dgm now dead -> zero the pooled-x accumulator (overlays dgm)
    zero_x_kernel<<<128, 256, 0, stream>>>(x);
    qkv_gemm_kernel<GP, 0><<<dim3(1536 / 128, (BATCH * GP) / 128), 256, 0, stream>>>(
        pg, wqkvp_t, qkvp, VT);
    qkv_gemm_kernel<GD, GP><<<dim3(1536 / 128, (BATCH * GD) / 128), 256, 0, stream>>>(
        dg, wqkvd_t, qkvd, VT);

    // 4. fused attention (logits + segmented masked softmax + mix + pooled sums)
    fused_attn_kernel<<<dim3(5, BATCH * NH), 256, 0, stream>>>(qkvp, qkvd, VT, mg, md, x);

    // 5. masked-mean: divide pooled sums by counts
    pool_div_kernel<<<BATCH, 1024, 0, stream>>>(x, mg, md);

    // 6. MLP head (proven thread-per-output structure; latency hidden by TLP)
    mlp_gemm_kernel<<<(BATCH * 1024) / 256, 256, 0, stream>>>(x, w1, b1, h1, 1024, 1024, 1);
    bn_kernel<<<1024 / 256, 256, 0, stream>>>(h1, g1, be1, 1024);
    mlp_gemm_kernel<<<(BATCH * 512) / 256, 256, 0, stream>>>(h1, w2, b2, h2, 1024, 512, 1);
    bn_kernel<<<512 / 256, 256, 0, stream>>>(h2, g2, be2, 512);
    mlp_gemm_kernel<<<(BATCH * 256) / 256, 256, 0, stream>>>(h2, w3, b3, h3, 512, 256, 1);
    bn_kernel<<<1, 256, 0, stream>>>(h3, g3, be3, 256);
    final_kernel<<<BATCH, 64, 0, stream>>>(h3, wo, bo, (float*)d_out);
}

// Round 4
// 751.937 us; speedup vs baseline: 2.3919x; 1.1597x over previous
//
#include <hip/hip_runtime.h>
#include <hip/hip_bf16.h>
#include <math.h>

// Problem constants (FusionDTI)
#define BATCH 32
#define LP 2048
#define LDRUG 512
#define DP 1280
#define DD 768
#define GP 256      // LP/8
#define GD 64       // LDRUG/8
#define HID 512
#define NH 8
#define HD 64
#define NKEY 320    // GP + GD concatenated keys
#define PST 328     // padded P row stride (f16) -> 2-way max bank conflict

typedef unsigned short ushort_t;
typedef __attribute__((ext_vector_type(8))) __bf16 bf16x8;
typedef __attribute__((ext_vector_type(8))) _Float16 f16x8;
typedef __attribute__((ext_vector_type(4))) float f32x4;

__device__ __forceinline__ ushort_t f2bf(float f) {
    unsigned int u = __float_as_uint(f);
    u += 0x7fff + ((u >> 16) & 1);          // round-to-nearest-even
    return (ushort_t)(u >> 16);
}

// ---------------------------------------------------------------------------
// Group mean -> bf16, vectorized float4 (4 d per thread)
// ---------------------------------------------------------------------------
__global__ void group_mean_kernel(const float* __restrict__ in,
                                  ushort_t* __restrict__ out, int D4, int total4) {
    int o = blockIdx.x * blockDim.x + threadIdx.x;
    if (o >= total4) return;
    int d = o % D4;
    long row = o / D4;
    const float4* p = (const float4*)in + row * 8 * (long)D4 + d;
    float4 s = {0.f, 0.f, 0.f, 0.f};
#pragma unroll
    for (int j = 0; j < 8; ++j) {
        float4 v = p[(long)j * D4];
        s.x += v.x; s.y += v.y; s.z += v.z; s.w += v.w;
    }
    uint2 r;
    r.x = (unsigned)f2bf(s.x * 0.125f) | ((unsigned)f2bf(s.y * 0.125f) << 16);
    r.y = (unsigned)f2bf(s.z * 0.125f) | ((unsigned)f2bf(s.w * 0.125f) << 16);
    *(uint2*)(out + (size_t)o * 4) = r;
}

__global__ void group_mask_kernel(const int* __restrict__ m,
                                  int* __restrict__ out, int total) {
    int o = blockIdx.x * blockDim.x + threadIdx.x;
    if (o >= total) return;
    const int* p = m + (long)o * 8;
    int any = 0;
#pragma unroll
    for (int j = 0; j < 8; ++j) any |= p[j];
    out[o] = any ? 1 : 0;
}

// ---------------------------------------------------------------------------
// Fused transpose+cast of all 8 weight matrices in ONE launch.
// ---------------------------------------------------------------------------
struct TransJobs {
    const float* src[8];
    ushort_t* dst[8];
    int K[8], N[8], base[8];   // base = first global tile index of job
};
__global__ __launch_bounds__(256) void transpose_cast8_kernel(TransJobs J) {
    __shared__ float tile[32][33];
    int tidx = blockIdx.x;
    int j = 0;
#pragma unroll
    for (int i = 1; i < 8; ++i) if (tidx >= J.base[i]) j = i;
    const float* W = J.src[j];
    ushort_t* Wt = J.dst[j];
    int K = J.K[j], N = J.N[j];
    int local = tidx - J.base[j];
    int kt = local % (K / 32), nt = local / (K / 32);
    int k0 = kt * 32, n0 = nt * 32;
    int tx = threadIdx.x & 31, ty = threadIdx.x >> 5;   // ty 0..7
#pragma unroll
    for (int i = 0; i < 32; i += 8)
        tile[ty + i][tx] = W[(size_t)(k0 + ty + i) * N + n0 + tx];
    __syncthreads();
#pragma unroll
    for (int i = 0; i < 32; i += 8)
        Wt[(size_t)(n0 + ty + i) * K + k0 + tx] = f2bf(tile[tx][ty + i]);
}

// ---------------------------------------------------------------------------
// MFMA bf16 GEMM (m97 structure): C = A @ Bt^T + bias, bf16 out.
// ---------------------------------------------------------------------------
__global__ __launch_bounds__(256) void mfma_gemm_kernel(
        const ushort_t* __restrict__ A, const ushort_t* __restrict__ Bt,
        const float* __restrict__ bias, ushort_t* __restrict__ C,
        int M, int N, int K) {
    __shared__ ushort_t As[128 * 32];
    __shared__ ushort_t Bs[128 * 32];
    const int t = threadIdx.x;
    const int m0 = blockIdx.y * 128, n0 = blockIdx.x * 128;
    const int wavebase = (t >> 6) * 64;
    const int lane = t & 63;
    const int lrow = lane & 15, quad = lane >> 4;
    const int m_base = ((t >> 6) >> 1) * 64;
    const int n_base = ((t >> 6) & 1) * 64;
    f32x4 acc[4][4] = {};

    for (int k0 = 0; k0 < K; k0 += 32) {
#pragma unroll
        for (int it = 0; it < 2; ++it) {
            int c = it * 256 + t;
            int row = c >> 2, kc = (c & 3) * 8;
            __builtin_amdgcn_global_load_lds(
                (const __attribute__((address_space(1))) void*)(A + (size_t)(m0 + row) * K + k0 + kc),
                (__attribute__((address_space(3))) void*)(As + (size_t)(it * 256 + wavebase) * 8),
                16, 0, 0);
            __builtin_amdgcn_global_load_lds(
                (const __attribute__((address_space(1))) void*)(Bt + (size_t)(n0 + row) * K + k0 + kc),
                (__attribute__((address_space(3))) void*)(Bs + (size_t)(it * 256 + wavebase) * 8),
                16, 0, 0);
        }
        __syncthreads();
        bf16x8 af[4], bfr[4];
#pragma unroll
        for (int i = 0; i < 4; ++i)
            af[i] = *(const bf16x8*)(As + (m_base + i * 16 + lrow) * 32 + quad * 8);
#pragma unroll
        for (int j = 0; j < 4; ++j)
            bfr[j] = *(const bf16x8*)(Bs + (n_base + j * 16 + lrow) * 32 + quad * 8);
#pragma unroll
        for (int i = 0; i < 4; ++i)
#pragma unroll
            for (int j = 0; j < 4; ++j)
                acc[i][j] = __builtin_amdgcn_mfma_f32_16x16x32_bf16(af[i], bfr[j], acc[i][j], 0, 0, 0);
        __syncthreads();
    }
#pragma unroll
    for (int i = 0; i < 4; ++i) {
#pragma unroll
        for (int j = 0; j < 4; ++j) {
            int n = n0 + n_base + j * 16 + lrow;
            float bv = bias ? bias[n] : 0.f;
#pragma unroll
            for (int r = 0; r < 4; ++r) {
                int m = m0 + m_base + i * 16 + quad * 4 + r;
                C[(size_t)m * N + n] = f2bf(acc[i][j][r] + bv);
            }
        }
    }
}

// ---------------------------------------------------------------------------
// QKV GEMM: A[M,512] bf16 @ Wt[1536,512]^T -> qkv fp16 [M][1536].
// Q,K columns (n<1024) stored to C; V columns only scattered into VT.
// ---------------------------------------------------------------------------
template<int G, int KEYOFF>
__global__ __launch_bounds__(256) void qkv_gemm_kernel(
        const ushort_t* __restrict__ A, const ushort_t* __restrict__ Bt,
        _Float16* __restrict__ C, _Float16* __restrict__ VT) {
    const int K = 512, N = 1536;
    __shared__ ushort_t As[128 * 32];
    __shared__ ushort_t Bs[128 * 32];
    const int t = threadIdx.x;
    const int m0 = blockIdx.y * 128, n0 = blockIdx.x * 128;
    const int wavebase = (t >> 6) * 64;
    const int lane = t & 63;
    const int lrow = lane & 15, quad = lane >> 4;
    const int m_base = ((t >> 6) >> 1) * 64;
    const int n_base = ((t >> 6) & 1) * 64;
    f32x4 acc[4][4] = {};

    for (int k0 = 0; k0 < K; k0 += 32) {
#pragma unroll
        for (int it = 0; it < 2; ++it) {
            int c = it * 256 + t;
            int row = c >> 2, kc = (c & 3) * 8;
            __builtin_amdgcn_global_load_lds(
                (const __attribute__((address_space(1))) void*)(A + (size_t)(m0 + row) * K + k0 + kc),
                (__attribute__((address_space(3))) void*)(As + (size_t)(it * 256 + wavebase) * 8),
                16, 0, 0);
            __builtin_amdgcn_global_load_lds(
                (const __attribute__((address_space(1))) void*)(Bt + (size_t)(n0 + row) * K + k0 + kc),
                (__attribute__((address_space(3))) void*)(Bs + (size_t)(it * 256 + wavebase) * 8),
                16, 0, 0);
        }
        __syncthreads();
        bf16x8 af[4], bfr[4];
#pragma unroll
        for (int i = 0; i < 4; ++i)
            af[i] = *(const bf16x8*)(As + (m_base + i * 16 + lrow) * 32 + quad * 8);
#pragma unroll
        for (int j = 0; j < 4; ++j)
            bfr[j] = *(const bf16x8*)(Bs + (n_base + j * 16 + lrow) * 32 + quad * 8);
#pragma unroll
        for (int i = 0; i < 4; ++i)
#pragma unroll
            for (int j = 0; j < 4; ++j)
                acc[i][j] = __builtin_amdgcn_mfma_f32_16x16x32_bf16(af[i], bfr[j], acc[i][j], 0, 0, 0);
        __syncthreads();
    }
#pragma unroll
    for (int i = 0; i < 4; ++i) {
#pragma unroll
        for (int j = 0; j < 4; ++j) {
            int n = n0 + n_base + j * 16 + lrow;
            int hh = (n - 1024) >> 6;       // head, valid when n >= 1024
            int dd = n & 63;
#pragma unroll
            for (int r = 0; r < 4; ++r) {
                int m = m0 + m_base + i * 16 + quad * 4 + r;
                _Float16 hv = (_Float16)acc[i][j][r];
                if (n < 1024) {
                    C[(size_t)m * N + n] = hv;
                } else {
                    int b = m / G, g = m % G;
                    VT[((size_t)(b * 8 + hh) * 64 + dd) * NKEY + KEYOFF + g] = hv;
                }
            }
        }
    }
}

// ---------------------------------------------------------------------------
// Fused attention: per (mtile, b*h) block computes 64 q-rows:
//   S = Q@K^T (f32, in-register) -> segmented masked softmax (in-register,
//   16-lane shfl reductions) -> P (f16, padded LDS) -> O = P@V -> column sums
//   atomically accumulated into x[B,1024] (masked-mean numerator).
// ---------------------------------------------------------------------------
__global__ __launch_bounds__(256) void fused_attn_kernel(
        const _Float16* __restrict__ qkvp, const _Float16* __restrict__ qkvd,
        const _Float16* __restrict__ VT,
        const int* __restrict__ mg, const int* __restrict__ md,
        float* __restrict__ x) {
    __shared__ _Float16 Ks[NKEY * 64];
    __shared__ _Float16 Vs[64 * NKEY];
    __shared__ _Float16 Ps[64 * PST];
    __shared__ int cm[NKEY];
    const int t = threadIdx.x;
    const int mtile = blockIdx.x, bh = blockIdx.y;
    const int b = bh >> 3, h = bh & 7;
    const int lane = t & 63, wid = t >> 6;
    const int lrow = lane & 15, quad = lane >> 4;

    if (t < GP) cm[t] = mg[b * GP + t];
    if (t < GD) cm[GP + t] = md[b * GD + t];

    // stage K rows (concat prot+drug keys), swizzled 16B columns
    for (int c = wid; c < 40; c += 4) {
        int row = c * 8 + (lane >> 3);
        int g16 = (lane & 7) ^ (row & 7);
        const _Float16* src = (row < GP)
            ? qkvp + ((size_t)(b * GP + row) * 1536 + 512 + h * HD) + g16 * 8
            : qkvd + ((size_t)(b * GD + row - GP) * 1536 + 512 + h * HD) + g16 * 8;
        __builtin_amdgcn_global_load_lds(
            (const __attribute__((address_space(1))) void*)src,
            (__attribute__((address_space(3))) void*)(Ks + (size_t)c * 512),
            16, 0, 0);
    }
    // stage V^T [d][key], swizzled 16B columns within 8-groups
    for (int c = wid; c < 40; c += 4) {
        int f = c * 64 + lane;
        int d = f / 40, c16 = f - d * 40;
        int gc = c16 ^ (d & 7);              // d&7 < 8: only low 3 bits flip
        const _Float16* src = VT + ((size_t)bh * 64 + d) * NKEY + gc * 8;
        __builtin_amdgcn_global_load_lds(
            (const __attribute__((address_space(1))) void*)src,
            (__attribute__((address_space(3))) void*)(Vs + (size_t)c * 512),
            16, 0, 0);
    }

    // Q fragments straight from global into registers
    const _Float16* Qb = (mtile < 4)
        ? qkvp + ((size_t)(b * GP + mtile * 64) * 1536 + h * HD)
        : qkvd + ((size_t)(b * GD) * 1536 + h * HD);
    const _Float16* qr = Qb + (size_t)(wid * 16 + lrow) * 1536 + quad * 8;
    f16x8 qf0 = *(const f16x8*)(qr);
    f16x8 qf1 = *(const f16x8*)(qr + 32);

    __syncthreads();

    // logits: sacc[nt] holds S[q = wid*16 + quad*4+r][key = nt*16 + lrow]
    f32x4 sacc[20] = {};
#pragma unroll
    for (int nt = 0; nt < 20; ++nt) {
        int key = nt * 16 + lrow;
        int x0 = (quad ^ (key & 7)) * 8;
        int x1 = ((4 + quad) ^ (key & 7)) * 8;
        f16x8 k0 = *(const f16x8*)(Ks + key * 64 + x0);
        f16x8 k1 = *(const f16x8*)(Ks + key * 64 + x1);
        sacc[nt] = __builtin_amdgcn_mfma_f32_16x16x32_f16(qf0, k0, sacc[nt], 0, 0, 0);
        sacc[nt] = __builtin_amdgcn_mfma_f32_16x16x32_f16(qf1, k1, sacc[nt], 0, 0, 0);
    }

    // segmented masked softmax, fully in registers
    int cmk[20];
#pragma unroll
    for (int nt = 0; nt < 20; ++nt) cmk[nt] = cm[nt * 16 + lrow];
    const int rbase = mtile * 64 + wid * 16 + quad * 4;
#pragma unroll
    for (int r = 0; r < 4; ++r) {
        int mrow = cm[rbase + r];
        float xv[20];
#pragma unroll
        for (int nt = 0; nt < 20; ++nt)
            xv[nt] = sacc[nt][r] - (cmk[nt] ? 0.f : 1e6f);
        // prot segment (keys 0..255 -> nt 0..15)
        float mx = xv[0];
#pragma unroll
        for (int nt = 1; nt < 16; ++nt) mx = fmaxf(mx, xv[nt]);
#pragma unroll
        for (int off = 1; off < 16; off <<= 1) mx = fmaxf(mx, __shfl_xor(mx, off));
        float e[20];
        float s = 0.f;
#pragma unroll
        for (int nt = 0; nt < 16; ++nt) { e[nt] = __expf(xv[nt] - mx); s += e[nt]; }
#pragma unroll
        for (int off = 1; off < 16; off <<= 1) s += __shfl_xor(s, off);
        float sp = mrow ? (1.f / s) : 0.f;
        // drug segment (keys 256..319 -> nt 16..19)
        float mx2 = fmaxf(fmaxf(xv[16], xv[17]), fmaxf(xv[18], xv[19]));
#pragma unroll
        for (int off = 1; off < 16; off <<= 1) mx2 = fmaxf(mx2, __shfl_xor(mx2, off));
        float s2 = 0.f;
#pragma unroll
        for (int nt = 16; nt < 20; ++nt) { e[nt] = __expf(xv[nt] - mx2); s2 += e[nt]; }
#pragma unroll
        for (int off = 1; off < 16; off <<= 1) s2 += __shfl_xor(s2, off);
        float sp2 = mrow ? (1.f / s2) : 0.f;
        int m = wid * 16 + quad * 4 + r;
#pragma unroll
        for (int nt = 0; nt < 16; ++nt)
            Ps[m * PST + nt * 16 + lrow] = (_Float16)(e[nt] * sp);
#pragma unroll
        for (int nt = 16; nt < 20; ++nt)
            Ps[m * PST + nt * 16 + lrow] = (_Float16)(e[nt] * sp2);
    }
    __syncthreads();

    // mix: O[q][d] = P[q][:] @ V[:][d]
    f32x4 oacc[4] = {};
#pragma unroll
    for (int kt = 0; kt < 10; ++kt) {
        f16x8 pa = *(const f16x8*)(Ps + (wid * 16 + lrow) * PST + kt * 32 + quad * 8);
#pragma unroll
        for (int nf = 0; nf < 4; ++nf) {
            int d = nf * 16 + lrow;
            int c16 = (kt * 4 + quad) ^ (d & 7);
            f16x8 vb = *(const f16x8*)(Vs + d * NKEY + c16 * 8);
            oacc[nf] = __builtin_amdgcn_mfma_f32_16x16x32_f16(pa, vb, oacc[nf], 0, 0, 0);
        }
    }

    // masked-mean numerator: column-sum the wave's 16 q-rows, atomically
    // accumulate *0.5 into x (prot rows -> x[:,0:512], drug -> x[:,512:1024])
    const int xoff = (mtile < 4) ? 0 : 512;
#pragma unroll
    for (int nf = 0; nf < 4; ++nf) {
        float cs = oacc[nf][0] + oacc[nf][1] + oacc[nf][2] + oacc[nf][3];
        cs += __shfl_xor(cs, 16);
        cs += __shfl_xor(cs, 32);
        if (quad == 0)
            atomicAdd(x + (size_t)b * 1024 + xoff + h * HD + nf * 16 + lrow, 0.5f * cs);
    }
}

__global__ void zero_x_kernel(float* __restrict__ x) {
    x[blockIdx.x * 256 + threadIdx.x] = 0.f;
}

// divide pooled sums by valid-group counts
__global__ void pool_div_kernel(float* __restrict__ x,
                                const int* __restrict__ mg, const int* __restrict__ md) {
    const int b = blockIdx.x, t = threadIdx.x;   // 1024 threads
    __shared__ float inv[2];
    if (t == 0) { int s = 0; for (int i = 0; i < GP; ++i) s += mg[b * GP + i] ? 1 : 0; inv[0] = 1.f / (float)s; }
    else if (t == 1) { int s = 0; for (int i = 0; i < GD; ++i) s += md[b * GD + i] ? 1 : 0; inv[1] = 1.f / (float)s; }
    __syncthreads();
    x[(size_t)b * 1024 + t] *= inv[t >> 9];
}

// ---------------------------------------------------------------------------
// Block-tiled MLP GEMM: grid (M=32, N/64); block = 64 n-lanes x 4 K-slices.
// X row staged in LDS (kills the global broadcast on the critical path);
// W reads coalesced 256 B/wave; K/4 iterations per thread; LDS reduce.
// Y = raw sum (bias+relu+BN fused in bn_relu_kernel).
// ---------------------------------------------------------------------------
template<int K, int N>
__global__ __launch_bounds__(256) void mlp_gemm_tiled(
        const float* __restrict__ X, const float* __restrict__ W,
        float* __restrict__ Y) {
    __shared__ float Xs[K];
    __shared__ float red[4][64];
    const int m = blockIdx.x, n0 = blockIdx.y * 64;
    const int t = threadIdx.x;
    const int nl = t & 63, ks = t >> 6;
    for (int i = t; i < K; i += 256) Xs[i] = X[(size_t)m * K + i];
    __syncthreads();
    const int KC = K / 4;
    const float* Wp = W + (size_t)(ks * KC) * N + n0 + nl;
    const float* Xp = Xs + ks * KC;
    float acc = 0.f;
#pragma unroll 8
    for (int i = 0; i < KC; ++i)
        acc = fmaf(Xp[i], Wp[(size_t)i * N], acc);
    red[ks][nl] = acc;
    __syncthreads();
    if (t < 64) {
        float s = red[0][t] + red[1][t] + red[2][t] + red[3][t];
        Y[(size_t)m * N + n0 + t] = s;
    }
}

// ---------------------------------------------------------------------------
// Fused bias + ReLU + BatchNorm: grid N/64; block = 64 cols x 4 row-groups.
// Coalesced reads/writes; biased variance via E[x^2]-mu^2 (matches var(0)).
// ---------------------------------------------------------------------------
template<int N>
__global__ __launch_bounds__(256) void bn_relu_kernel(
        const float* __restrict__ Ysum, const float* __restrict__ bias,
        const float* __restrict__ gamma, const float* __restrict__ beta,
        float* __restrict__ Out) {
    const int t = threadIdx.x;
    const int tc = t & 63, rg = t >> 6;
    const int c = blockIdx.x * 64 + tc;
    float bv = bias[c];
    float h[8], ps = 0.f, pq = 0.f;
#pragma unroll
    for (int r = 0; r < 8; ++r) {
        float v = fmaxf(Ysum[(size_t)(rg * 8 + r) * N + c] + bv, 0.f);
        h[r] = v; ps += v; pq += v * v;
    }
    __shared__ float red[2][4][64];
    red[0][rg][tc] = ps; red[1][rg][tc] = pq;
    __syncthreads();
    float mu  = (red[0][0][tc] + red[0][1][tc] + red[0][2][tc] + red[0][3][tc]) * (1.f / 32.f);
    float msq = (red[1][0][tc] + red[1][1][tc] + red[1][2][tc] + red[1][3][tc]) * (1.f / 32.f);
    float sc = gamma[c] * rsqrtf(msq - mu * mu + 1e-5f);
    float sh = beta[c] - mu * sc;
#pragma unroll
    for (int r = 0; r < 8; ++r)
        Out[(size_t)(rg * 8 + r) * N + c] = h[r] * sc + sh;
}

__global__ void final_kernel(const float* __restrict__ H, const float* __restrict__ wo,
                             const float* __restrict__ bo, float* __restrict__ out) {
    const int b = blockIdx.x, lane = threadIdx.x;   // 64 threads
    float p = 0.f;
#pragma unroll
    for (int j = 0; j < 4; ++j) {
        int idx = lane + j * 64;
        p += H[b * 256 + idx] * wo[idx];
    }
#pragma unroll
    for (int off = 32; off >= 1; off >>= 1) p += __shfl_xor(p, off);
    if (lane == 0) out[b] = 1.f / (1.f + expf(-(p + bo[0])));
}

// ---------------------------------------------------------------------------
extern "C" void kernel_launch(void* const* d_in, const int* in_sizes, int n_in,
                              void* d_out, int out_size, void* d_ws, size_t ws_size,
                              hipStream_t stream) {
    const float* prot_embed = (const float*)d_in[0];
    const float* drug_embed = (const float*)d_in[1];
    const int* prot_mask = (const int*)d_in[2];
    const int* drug_mask = (const int*)d_in[3];
    const float* w_preg = (const float*)d_in[4];
    const float* b_preg = (const float*)d_in[5];
    const float* w_dreg = (const float*)d_in[6];
    const float* b_dreg = (const float*)d_in[7];
    const float* wqp = (const float*)d_in[8];
    const float* wkp = (const float*)d_in[9];
    const float* wvp = (const float*)d_in[10];
    const float* wqd = (const float*)d_in[11];
    const float* wkd = (const float*)d_in[12];
    const float* wvd = (const float*)d_in[13];
    const float* w1 = (const float*)d_in[14];  const float* b1 = (const float*)d_in[15];
    const float* g1 = (const float*)d_in[16];  const float* be1 = (const float*)d_in[17];
    const float* w2 = (const float*)d_in[18];  const float* b2 = (const float*)d_in[19];
    const float* g2 = (const float*)d_in[20];  const float* be2 = (const float*)d_in[21];
    const float* w3 = (const float*)d_in[22];  const float* b3 = (const float*)d_in[23];
    const float* g3 = (const float*)d_in[24];  const float* be3 = (const float*)d_in[25];
    const float* wo = (const float*)d_in[26];  const float* bo = (const float*)d_in[27];

    // ---- workspace layout (elements) ----
    ushort_t* pgm = (ushort_t*)d_ws;                 // [8192][1280] bf16
    ushort_t* dgm = pgm + 10485760;                  // [2048][768] bf16
    ushort_t* wpreg_t = dgm + 1572864;               // [512][1280]
    ushort_t* wdreg_t = wpreg_t + 655360;            // [512][768]
    ushort_t* wqkvp_t = wdreg_t + 393216;            // [1536][512]
    ushort_t* wqkvd_t = wqkvp_t + 786432;            // [1536][512]
    ushort_t* pg = wqkvd_t + 786432;                 // [8192][512] bf16
    ushort_t* dg = pg + 4194304;                     // [2048][512] bf16
    _Float16* qkvp = (_Float16*)(dg + 1048576);      // [8192][1536] f16
    _Float16* qkvd = qkvp + 12582912;                // [2048][1536] f16
    _Float16* VT   = qkvd + 3145728;                 // [256][64][320] f16
    int* mg = (int*)(VT + 5242880);                  // [8192]
    int* md = mg + 8192;                             // [2048]
    // overlay: dgm dead after drug regression GEMM -> x / MLP tmps
    // dgm region = 3,145,728 B = 786,432 floats; need 144K floats -> fits
    float* x  = (float*)dgm;                         // [32][1024]
    float* s1 = x + 32768;                           // raw sums layer1 [32][1024]
    float* h1 = s1 + 32768;                          // bn out layer1
    float* s2 = h1 + 32768;                          // [32][512]
    float* h2 = s2 + 16384;
    float* s3 = h2 + 16384;                          // [32][256]
    float* h3 = s3 + 8192;

    // 1. group means (mean commutes with the linear regression layers) -> bf16
    group_mean_kernel<<<(BATCH * GP * DP / 4) / 256, 256, 0, stream>>>(prot_embed, pgm, DP / 4, BATCH * GP * DP / 4);
    group_mean_kernel<<<(BATCH * GD * DD / 4) / 256, 256, 0, stream>>>(drug_embed, dgm, DD / 4, BATCH * GD * DD / 4);
    group_mask_kernel<<<(BATCH * GP) / 256, 256, 0, stream>>>(prot_mask, mg, BATCH * GP);
    group_mask_kernel<<<(BATCH * GD) / 256, 256, 0, stream>>>(drug_mask, md, BATCH * GD);

    // 2. all 8 weight transposes in one launch
    TransJobs J;
    J.src[0] = w_preg; J.dst[0] = wpreg_t; J.K[0] = DP;  J.N[0] = HID;
    J.src[1] = w_dreg; J.dst[1] = wdreg_t; J.K[1] = DD;  J.N[1] = HID;
    J.src[2] = wqp; J.dst[2] = wqkvp_t;              J.K[2] = HID; J.N[2] = HID;
    J.src[3] = wkp; J.dst[3] = wqkvp_t + 512 * 512;  J.K[3] = HID; J.N[3] = HID;
    J.src[4] = wvp; J.dst[4] = wqkvp_t + 1024 * 512; J.K[4] = HID; J.N[4] = HID;
    J.src[5] = wqd; J.dst[5] = wqkvd_t;              J.K[5] = HID; J.N[5] = HID;
    J.src[6] = wkd; J.dst[6] = wqkvd_t + 512 * 512;  J.K[6] = HID; J.N[6] = HID;
    J.src[7] = wvd; J.dst[7] = wqkvd_t + 1024 * 512; J.K[7] = HID; J.N[7] = HID;
    {
        int base = 0;
        for (int i = 0; i < 8; ++i) { J.base[i] = base; base += (J.K[i] / 32) * (J.N[i] / 32); }
        transpose_cast8_kernel<<<base, 256, 0, stream>>>(J);
    }

    // 3. regression GEMMs (bf16 out, bias), then fused QKV GEMMs (f16 out + VT)
    mfma_gemm_kernel<<<dim3(HID / 128, (BATCH * GP) / 128), 256, 0, stream>>>(
        pgm, wpreg_t, b_preg, pg, BATCH * GP, HID, DP);
    mfma_gemm_kernel<<<dim3(HID / 128, (BATCH * GD) / 128), 256, 0, stream>>>(
        dgm, wdreg_t, b_dreg, dg, BATCH * GD, HID, DD);
    // dgm now dead -> zero the pooled-x accumulator (overlays dgm)
    zero_x_kernel<<<128, 256, 0, stream>>>(x);
    qkv_gemm_kernel<GP, 0><<<dim3(1536 / 128, (BATCH * GP) / 128), 256, 0, stream>>>(
        pg, wqkvp_t, qkvp, VT);
    qkv_gemm_kernel<GD, GP><<<dim3(1536 / 128, (BATCH * GD) / 128), 256, 0, stream>>>(
        dg, wqkvd_t, qkvd, VT);

    // 4. fused attention (logits + segmented masked softmax + mix + pooled sums)
    fused_attn_kernel<<<dim3(5, BATCH * NH), 256, 0, stream>>>(qkvp, qkvd, VT, mg, md, x);

    // 5. masked-mean: divide pooled sums by counts
    pool_div_kernel<<<BATCH, 1024, 0, stream>>>(x, mg, md);

    // 6. MLP head: block-tiled GEMM (raw sums) + fused bias/ReLU/BN
    mlp_gemm_tiled<1024, 1024><<<dim3(BATCH, 1024 / 64), 256, 0, stream>>>(x, w1, s1);
    bn_relu_kernel<1024><<<1024 / 64, 256, 0, stream>>>(s1, b1, g1, be1, h1);
    mlp_gemm_tiled<1024, 512><<<dim3(BATCH, 512 / 64), 256, 0, stream>>>(h1, w2, s2);
    bn_relu_kernel<512><<<512 / 64, 256, 0, stream>>>(s2, b2, g2, be2, h2);
    mlp_gemm_tiled<512, 256><<<dim3(BATCH, 256 / 64), 256, 0, stream>>>(h2, w3, s3);
    bn_relu_kernel<256><<<256 / 64, 256, 0, stream>>>(s3, b3, g3, be3, h3);
    final_kernel<<<BATCH, 64, 0, stream>>>(h3, wo, bo, (float*)d_out);
}

// Round 5
// 721.370 us; speedup vs baseline: 2.4933x; 1.0424x over previous
//
#include <hip/hip_runtime.h>
#include <hip/hip_bf16.h>
#include <math.h>

// Problem constants (FusionDTI)
#define BATCH 32
#define LP 2048
#define LDRUG 512
#define DP 1280
#define DD 768
#define GP 256      // LP/8
#define GD 64       // LDRUG/8
#define HID 512
#define NH 8
#define HD 64
#define NKEY 320    // GP + GD concatenated keys

typedef unsigned short ushort_t;
typedef __attribute__((ext_vector_type(8))) __bf16 bf16x8;
typedef __attribute__((ext_vector_type(8))) _Float16 f16x8;
typedef __attribute__((ext_vector_type(4))) float f32x4;

__device__ __forceinline__ ushort_t f2bf(float f) {
    unsigned int u = __float_as_uint(f);
    u += 0x7fff + ((u >> 16) & 1);          // round-to-nearest-even
    return (ushort_t)(u >> 16);
}

// ---------------------------------------------------------------------------
// Group mean -> bf16, vectorized float4 (4 d per thread)
// ---------------------------------------------------------------------------
__global__ void group_mean_kernel(const float* __restrict__ in,
                                  ushort_t* __restrict__ out, int D4, int total4) {
    int o = blockIdx.x * blockDim.x + threadIdx.x;
    if (o >= total4) return;
    int d = o % D4;
    long row = o / D4;
    const float4* p = (const float4*)in + row * 8 * (long)D4 + d;
    float4 s = {0.f, 0.f, 0.f, 0.f};
#pragma unroll
    for (int j = 0; j < 8; ++j) {
        float4 v = p[(long)j * D4];
        s.x += v.x; s.y += v.y; s.z += v.z; s.w += v.w;
    }
    uint2 r;
    r.x = (unsigned)f2bf(s.x * 0.125f) | ((unsigned)f2bf(s.y * 0.125f) << 16);
    r.y = (unsigned)f2bf(s.z * 0.125f) | ((unsigned)f2bf(s.w * 0.125f) << 16);
    *(uint2*)(out + (size_t)o * 4) = r;
}

__global__ void group_mask_kernel(const int* __restrict__ m,
                                  int* __restrict__ out, int total) {
    int o = blockIdx.x * blockDim.x + threadIdx.x;
    if (o >= total) return;
    const int* p = m + (long)o * 8;
    int any = 0;
#pragma unroll
    for (int j = 0; j < 8; ++j) any |= p[j];
    out[o] = any ? 1 : 0;
}

// ---------------------------------------------------------------------------
// Fused transpose+cast of all 8 weight matrices in ONE launch.
// ---------------------------------------------------------------------------
struct TransJobs {
    const float* src[8];
    ushort_t* dst[8];
    int K[8], N[8], base[8];   // base = first global tile index of job
};
__global__ __launch_bounds__(256) void transpose_cast8_kernel(TransJobs J) {
    __shared__ float tile[32][33];
    int tidx = blockIdx.x;
    int j = 0;
#pragma unroll
    for (int i = 1; i < 8; ++i) if (tidx >= J.base[i]) j = i;
    const float* W = J.src[j];
    ushort_t* Wt = J.dst[j];
    int K = J.K[j], N = J.N[j];
    int local = tidx - J.base[j];
    int kt = local % (K / 32), nt = local / (K / 32);
    int k0 = kt * 32, n0 = nt * 32;
    int tx = threadIdx.x & 31, ty = threadIdx.x >> 5;   // ty 0..7
#pragma unroll
    for (int i = 0; i < 32; i += 8)
        tile[ty + i][tx] = W[(size_t)(k0 + ty + i) * N + n0 + tx];
    __syncthreads();
#pragma unroll
    for (int i = 0; i < 32; i += 8)
        Wt[(size_t)(n0 + ty + i) * K + k0 + tx] = f2bf(tile[tx][ty + i]);
}

// ---------------------------------------------------------------------------
// MFMA bf16 GEMM (m97 structure): C = A @ Bt^T + bias, bf16 out.
// ---------------------------------------------------------------------------
__global__ __launch_bounds__(256) void mfma_gemm_kernel(
        const ushort_t* __restrict__ A, const ushort_t* __restrict__ Bt,
        const float* __restrict__ bias, ushort_t* __restrict__ C,
        int M, int N, int K) {
    __shared__ ushort_t As[128 * 32];
    __shared__ ushort_t Bs[128 * 32];
    const int t = threadIdx.x;
    const int m0 = blockIdx.y * 128, n0 = blockIdx.x * 128;
    const int wavebase = (t >> 6) * 64;
    const int lane = t & 63;
    const int lrow = lane & 15, quad = lane >> 4;
    const int m_base = ((t >> 6) >> 1) * 64;
    const int n_base = ((t >> 6) & 1) * 64;
    f32x4 acc[4][4] = {};

    for (int k0 = 0; k0 < K; k0 += 32) {
#pragma unroll
        for (int it = 0; it < 2; ++it) {
            int c = it * 256 + t;
            int row = c >> 2, kc = (c & 3) * 8;
            __builtin_amdgcn_global_load_lds(
                (const __attribute__((address_space(1))) void*)(A + (size_t)(m0 + row) * K + k0 + kc),
                (__attribute__((address_space(3))) void*)(As + (size_t)(it * 256 + wavebase) * 8),
                16, 0, 0);
            __builtin_amdgcn_global_load_lds(
                (const __attribute__((address_space(1))) void*)(Bt + (size_t)(n0 + row) * K + k0 + kc),
                (__attribute__((address_space(3))) void*)(Bs + (size_t)(it * 256 + wavebase) * 8),
                16, 0, 0);
        }
        __syncthreads();
        bf16x8 af[4], bfr[4];
#pragma unroll
        for (int i = 0; i < 4; ++i)
            af[i] = *(const bf16x8*)(As + (m_base + i * 16 + lrow) * 32 + quad * 8);
#pragma unroll
        for (int j = 0; j < 4; ++j)
            bfr[j] = *(const bf16x8*)(Bs + (n_base + j * 16 + lrow) * 32 + quad * 8);
#pragma unroll
        for (int i = 0; i < 4; ++i)
#pragma unroll
            for (int j = 0; j < 4; ++j)
                acc[i][j] = __builtin_amdgcn_mfma_f32_16x16x32_bf16(af[i], bfr[j], acc[i][j], 0, 0, 0);
        __syncthreads();
    }
#pragma unroll
    for (int i = 0; i < 4; ++i) {
#pragma unroll
        for (int j = 0; j < 4; ++j) {
            int n = n0 + n_base + j * 16 + lrow;
            float bv = bias ? bias[n] : 0.f;
#pragma unroll
            for (int r = 0; r < 4; ++r) {
                int m = m0 + m_base + i * 16 + quad * 4 + r;
                C[(size_t)m * N + n] = f2bf(acc[i][j][r] + bv);
            }
        }
    }
}

// ---------------------------------------------------------------------------
// QKV GEMM: A[M,512] bf16 @ Wt[1536,512]^T -> qkv fp16 [M][1536].
// Q,K columns (n<1024) stored to C; V columns only scattered into VT.
// ---------------------------------------------------------------------------
template<int G, int KEYOFF>
__global__ __launch_bounds__(256) void qkv_gemm_kernel(
        const ushort_t* __restrict__ A, const ushort_t* __restrict__ Bt,
        _Float16* __restrict__ C, _Float16* __restrict__ VT) {
    const int K = 512, N = 1536;
    __shared__ ushort_t As[128 * 32];
    __shared__ ushort_t Bs[128 * 32];
    const int t = threadIdx.x;
    const int m0 = blockIdx.y * 128, n0 = blockIdx.x * 128;
    const int wavebase = (t >> 6) * 64;
    const int lane = t & 63;
    const int lrow = lane & 15, quad = lane >> 4;
    const int m_base = ((t >> 6) >> 1) * 64;
    const int n_base = ((t >> 6) & 1) * 64;
    f32x4 acc[4][4] = {};

    for (int k0 = 0; k0 < K; k0 += 32) {
#pragma unroll
        for (int it = 0; it < 2; ++it) {
            int c = it * 256 + t;
            int row = c >> 2, kc = (c & 3) * 8;
            __builtin_amdgcn_global_load_lds(
                (const __attribute__((address_space(1))) void*)(A + (size_t)(m0 + row) * K + k0 + kc),
                (__attribute__((address_space(3))) void*)(As + (size_t)(it * 256 + wavebase) * 8),
                16, 0, 0);
            __builtin_amdgcn_global_load_lds(
                (const __attribute__((address_space(1))) void*)(Bt + (size_t)(n0 + row) * K + k0 + kc),
                (__attribute__((address_space(3))) void*)(Bs + (size_t)(it * 256 + wavebase) * 8),
                16, 0, 0);
        }
        __syncthreads();
        bf16x8 af[4], bfr[4];
#pragma unroll
        for (int i = 0; i < 4; ++i)
            af[i] = *(const bf16x8*)(As + (m_base + i * 16 + lrow) * 32 + quad * 8);
#pragma unroll
        for (int j = 0; j < 4; ++j)
            bfr[j] = *(const bf16x8*)(Bs + (n_base + j * 16 + lrow) * 32 + quad * 8);
#pragma unroll
        for (int i = 0; i < 4; ++i)
#pragma unroll
            for (int j = 0; j < 4; ++j)
                acc[i][j] = __builtin_amdgcn_mfma_f32_16x16x32_bf16(af[i], bfr[j], acc[i][j], 0, 0, 0);
        __syncthreads();
    }
#pragma unroll
    for (int i = 0; i < 4; ++i) {
#pragma unroll
        for (int j = 0; j < 4; ++j) {
            int n = n0 + n_base + j * 16 + lrow;
            int hh = (n - 1024) >> 6;       // head, valid when n >= 1024
            int dd = n & 63;
#pragma unroll
            for (int r = 0; r < 4; ++r) {
                int m = m0 + m_base + i * 16 + quad * 4 + r;
                _Float16 hv = (_Float16)acc[i][j][r];
                if (n < 1024) {
                    C[(size_t)m * N + n] = hv;
                } else {
                    int b = m / G, g = m % G;
                    VT[((size_t)(b * 8 + hh) * 64 + dd) * NKEY + KEYOFF + g] = hv;
                }
            }
        }
    }
}

// ---------------------------------------------------------------------------
// Fused attention v2: per (mtile, b*h) block, 64 q-rows.
//   LDS: ONE 40960 B buffer KP, used first as staged K (40x[8rows x 64] f16,
//   XOR-swizzled 16B chunks), then REUSED as P (64 rows x 320, chunk index
//   XORed with row&7 -> conflict-free b128 reads). V is NOT staged: fragments
//   read directly from global VT (40 KB per (b,h), L2-resident).
//   LDS total ~42 KB -> 3 blocks/CU (was 125 KB -> 1 block/CU).
// ---------------------------------------------------------------------------
__global__ __launch_bounds__(256) void fused_attn_kernel(
        const _Float16* __restrict__ qkvp, const _Float16* __restrict__ qkvd,
        const _Float16* __restrict__ VT,
        const int* __restrict__ mg, const int* __restrict__ md,
        float* __restrict__ x) {
    __shared__ _Float16 KP[20480];      // 40960 B: K stage, then P
    __shared__ int cm[NKEY];
    const int t = threadIdx.x;
    const int mtile = blockIdx.x, bh = blockIdx.y;
    const int b = bh >> 3, h = bh & 7;
    const int lane = t & 63, wid = t >> 6;
    const int lrow = lane & 15, quad = lane >> 4;

    if (t < GP) cm[t] = mg[b * GP + t];
    if (t < GD) cm[GP + t] = md[b * GD + t];

    // stage K rows (concat prot+drug keys), swizzled 16B chunks within rows
    for (int c = wid; c < 40; c += 4) {
        int row = c * 8 + (lane >> 3);
        int g16 = (lane & 7) ^ (row & 7);
        const _Float16* src = (row < GP)
            ? qkvp + ((size_t)(b * GP + row) * 1536 + 512 + h * HD) + g16 * 8
            : qkvd + ((size_t)(b * GD + row - GP) * 1536 + 512 + h * HD) + g16 * 8;
        __builtin_amdgcn_global_load_lds(
            (const __attribute__((address_space(1))) void*)src,
            (__attribute__((address_space(3))) void*)(KP + (size_t)c * 512),
            16, 0, 0);
    }

    // Q fragments straight from global into registers
    const _Float16* Qb = (mtile < 4)
        ? qkvp + ((size_t)(b * GP + mtile * 64) * 1536 + h * HD)
        : qkvd + ((size_t)(b * GD) * 1536 + h * HD);
    const _Float16* qr = Qb + (size_t)(wid * 16 + lrow) * 1536 + quad * 8;
    f16x8 qf0 = *(const f16x8*)(qr);
    f16x8 qf1 = *(const f16x8*)(qr + 32);

    __syncthreads();

    // logits: sacc[nt] holds S[q = wid*16 + quad*4+r][key = nt*16 + lrow]
    f32x4 sacc[20] = {};
#pragma unroll
    for (int nt = 0; nt < 20; ++nt) {
        int key = nt * 16 + lrow;
        int x0 = (quad ^ (key & 7)) * 8;
        int x1 = ((4 + quad) ^ (key & 7)) * 8;
        f16x8 k0 = *(const f16x8*)(KP + key * 64 + x0);
        f16x8 k1 = *(const f16x8*)(KP + key * 64 + x1);
        sacc[nt] = __builtin_amdgcn_mfma_f32_16x16x32_f16(qf0, k0, sacc[nt], 0, 0, 0);
        sacc[nt] = __builtin_amdgcn_mfma_f32_16x16x32_f16(qf1, k1, sacc[nt], 0, 0, 0);
    }
    __syncthreads();    // all waves done reading K -> KP can become P

    // segmented masked softmax, fully in registers; P written swizzled to KP
    int cmk[20];
#pragma unroll
    for (int nt = 0; nt < 20; ++nt) cmk[nt] = cm[nt * 16 + lrow];
    const int rbase = mtile * 64 + wid * 16 + quad * 4;
#pragma unroll
    for (int r = 0; r < 4; ++r) {
        int mrow = cm[rbase + r];
        float xv[20];
#pragma unroll
        for (int nt = 0; nt < 20; ++nt)
            xv[nt] = sacc[nt][r] - (cmk[nt] ? 0.f : 1e6f);
        // prot segment (keys 0..255 -> nt 0..15)
        float mx = xv[0];
#pragma unroll
        for (int nt = 1; nt < 16; ++nt) mx = fmaxf(mx, xv[nt]);
#pragma unroll
        for (int off = 1; off < 16; off <<= 1) mx = fmaxf(mx, __shfl_xor(mx, off));
        float e[20];
        float s = 0.f;
#pragma unroll
        for (int nt = 0; nt < 16; ++nt) { e[nt] = __expf(xv[nt] - mx); s += e[nt]; }
#pragma unroll
        for (int off = 1; off < 16; off <<= 1) s += __shfl_xor(s, off);
        float sp = mrow ? (1.f / s) : 0.f;
        // drug segment (keys 256..319 -> nt 16..19)
        float mx2 = fmaxf(fmaxf(xv[16], xv[17]), fmaxf(xv[18], xv[19]));
#pragma unroll
        for (int off = 1; off < 16; off <<= 1) mx2 = fmaxf(mx2, __shfl_xor(mx2, off));
        float s2 = 0.f;
#pragma unroll
        for (int nt = 16; nt < 20; ++nt) { e[nt] = __expf(xv[nt] - mx2); s2 += e[nt]; }
#pragma unroll
        for (int off = 1; off < 16; off <<= 1) s2 += __shfl_xor(s2, off);
        float sp2 = mrow ? (1.f / s2) : 0.f;
        int m = wid * 16 + quad * 4 + r;
        // P[m][key]: chunk c16=key>>3 stored at (c16 ^ (m&7)); elem key&7
#pragma unroll
        for (int nt = 0; nt < 20; ++nt) {
            float pv = (nt < 16) ? e[nt] * sp : e[nt] * sp2;
            int c16 = (nt * 2 + (lrow >> 3)) ^ (m & 7);
            KP[m * 320 + c16 * 8 + (lrow & 7)] = (_Float16)pv;
        }
    }
    __syncthreads();

    // mix: O[q][d] = P[q][:] @ V[:][d]; V fragments straight from global
    const _Float16* Vb = VT + (size_t)bh * HD * NKEY;
    f32x4 oacc[4] = {};
#pragma unroll
    for (int kt = 0; kt < 10; ++kt) {
        int q = wid * 16 + lrow;
        int c16 = (kt * 4 + quad) ^ (q & 7);
        f16x8 pa = *(const f16x8*)(KP + q * 320 + c16 * 8);
#pragma unroll
        for (int nf = 0; nf < 4; ++nf) {
            int d = nf * 16 + lrow;
            f16x8 vb = *(const f16x8*)(Vb + (size_t)d * NKEY + kt * 32 + quad * 8);
            oacc[nf] = __builtin_amdgcn_mfma_f32_16x16x32_f16(pa, vb, oacc[nf], 0, 0, 0);
        }
    }

    // masked-mean numerator: column-sum the wave's 16 q-rows, atomically
    // accumulate *0.5 into x (prot rows -> x[:,0:512], drug -> x[:,512:1024])
    const int xoff = (mtile < 4) ? 0 : 512;
#pragma unroll
    for (int nf = 0; nf < 4; ++nf) {
        float cs = oacc[nf][0] + oacc[nf][1] + oacc[nf][2] + oacc[nf][3];
        cs += __shfl_xor(cs, 16);
        cs += __shfl_xor(cs, 32);
        if (quad == 0)
            atomicAdd(x + (size_t)b * 1024 + xoff + h * HD + nf * 16 + lrow, 0.5f * cs);
    }
}

// zero the x..h3 scratch region (147456 floats)
__global__ void zero_scratch_kernel(float* __restrict__ p) {
    p[blockIdx.x * 256 + threadIdx.x] = 0.f;
}

// divide pooled sums by valid-group counts (wave-parallel counts)
__global__ void pool_div_kernel(float* __restrict__ x,
                                const int* __restrict__ mg, const int* __restrict__ md) {
    const int b = blockIdx.x, t = threadIdx.x;   // 1024 threads
    __shared__ float inv[2];
    if (t < 64) {
        int s = 0;
        for (int i = t; i < GP; i += 64) s += mg[b * GP + i] ? 1 : 0;
#pragma unroll
        for (int off = 32; off >= 1; off >>= 1) s += __shfl_xor(s, off);
        if (t == 0) inv[0] = 1.f / (float)s;
    } else if (t < 128) {
        int l = t - 64;
        int s = md[b * GD + l] ? 1 : 0;
#pragma unroll
        for (int off = 32; off >= 1; off >>= 1) s += __shfl_xor(s, off);
        if (l == 0) inv[1] = 1.f / (float)s;
    }
    __syncthreads();
    x[(size_t)b * 1024 + t] *= inv[t >> 9];
}

// ---------------------------------------------------------------------------
// Block-tiled split-K MLP GEMM: grid (M=32, N/64, KS=4). Block = 64 n-lanes
// x 4 K-slices over a K/4 chunk; X chunk in LDS; atomicAdd partial into Y.
// Per-thread chain = K/16 iterations -> latency-bound regime avoided.
// ---------------------------------------------------------------------------
template<int K, int N>
__global__ __launch_bounds__(256) void mlp_gemm_tiled(
        const float* __restrict__ X, const float* __restrict__ W,
        float* __restrict__ Y) {
    const int KB = K / 4;                 // per-block K chunk
    __shared__ float Xs[KB];
    __shared__ float red[4][64];
    const int m = blockIdx.x, n0 = blockIdx.y * 64, kb = blockIdx.z;
    const int t = threadIdx.x;
    const int nl = t & 63, ks = t >> 6;
    const float* Xg = X + (size_t)m * K + (size_t)kb * KB;
    for (int i = t; i < KB; i += 256) Xs[i] = Xg[i];
    __syncthreads();
    const int KC = KB / 4;
    const float* Wp = W + (size_t)(kb * KB + ks * KC) * N + n0 + nl;
    const float* Xp = Xs + ks * KC;
    float acc = 0.f;
#pragma unroll 8
    for (int i = 0; i < KC; ++i)
        acc = fmaf(Xp[i], Wp[(size_t)i * N], acc);
    red[ks][nl] = acc;
    __syncthreads();
    if (t < 64) {
        float s = red[0][t] + red[1][t] + red[2][t] + red[3][t];
        atomicAdd(Y + (size_t)m * N + n0 + t, s);
    }
}

// ---------------------------------------------------------------------------
// Fused bias + ReLU + BatchNorm: grid N/64; block = 64 cols x 4 row-groups.
// ---------------------------------------------------------------------------
template<int N>
__global__ __launch_bounds__(256) void bn_relu_kernel(
        const float* __restrict__ Ysum, const float* __restrict__ bias,
        const float* __restrict__ gamma, const float* __restrict__ beta,
        float* __restrict__ Out) {
    const int t = threadIdx.x;
    const int tc = t & 63, rg = t >> 6;
    const int c = blockIdx.x * 64 + tc;
    float bv = bias[c];
    float h[8], ps = 0.f, pq = 0.f;
#pragma unroll
    for (int r = 0; r < 8; ++r) {
        float v = fmaxf(Ysum[(size_t)(rg * 8 + r) * N + c] + bv, 0.f);
        h[r] = v; ps += v; pq += v * v;
    }
    __shared__ float red[2][4][64];
    red[0][rg][tc] = ps; red[1][rg][tc] = pq;
    __syncthreads();
    float mu  = (red[0][0][tc] + red[0][1][tc] + red[0][2][tc] + red[0][3][tc]) * (1.f / 32.f);
    float msq = (red[1][0][tc] + red[1][1][tc] + red[1][2][tc] + red[1][3][tc]) * (1.f / 32.f);
    float sc = gamma[c] * rsqrtf(msq - mu * mu + 1e-5f);
    float sh = beta[c] - mu * sc;
#pragma unroll
    for (int r = 0; r < 8; ++r)
        Out[(size_t)(rg * 8 + r) * N + c] = h[r] * sc + sh;
}

__global__ void final_kernel(const float* __restrict__ H, const float* __restrict__ wo,
                             const float* __restrict__ bo, float* __restrict__ out) {
    const int b = blockIdx.x, lane = threadIdx.x;   // 64 threads
    float p = 0.f;
#pragma unroll
    for (int j = 0; j < 4; ++j) {
        int idx = lane + j * 64;
        p += H[b * 256 + idx] * wo[idx];
    }
#pragma unroll
    for (int off = 32; off >= 1; off >>= 1) p += __shfl_xor(p, off);
    if (lane == 0) out[b] = 1.f / (1.f + expf(-(p + bo[0])));
}

// ---------------------------------------------------------------------------
extern "C" void kernel_launch(void* const* d_in, const int* in_sizes, int n_in,
                              void* d_out, int out_size, void* d_ws, size_t ws_size,
                              hipStream_t stream) {
    const float* prot_embed = (const float*)d_in[0];
    const float* drug_embed = (const float*)d_in[1];
    const int* prot_mask = (const int*)d_in[2];
    const int* drug_mask = (const int*)d_in[3];
    const float* w_preg = (const float*)d_in[4];
    const float* b_preg = (const float*)d_in[5];
    const float* w_dreg = (const float*)d_in[6];
    const float* b_dreg = (const float*)d_in[7];
    const float* wqp = (const float*)d_in[8];
    const float* wkp = (const float*)d_in[9];
    const float* wvp = (const float*)d_in[10];
    const float* wqd = (const float*)d_in[11];
    const float* wkd = (const float*)d_in[12];
    const float* wvd = (const float*)d_in[13];
    const float* w1 = (const float*)d_in[14];  const float* b1 = (const float*)d_in[15];
    const float* g1 = (const float*)d_in[16];  const float* be1 = (const float*)d_in[17];
    const float* w2 = (const float*)d_in[18];  const float* b2 = (const float*)d_in[19];
    const float* g2 = (const float*)d_in[20];  const float* be2 = (const float*)d_in[21];
    const float* w3 = (const float*)d_in[22];  const float* b3 = (const float*)d_in[23];
    const float* g3 = (const float*)d_in[24];  const float* be3 = (const float*)d_in[25];
    const float* wo = (const float*)d_in[26];  const float* bo = (const float*)d_in[27];

    // ---- workspace layout (elements) ----
    ushort_t* pgm = (ushort_t*)d_ws;                 // [8192][1280] bf16
    ushort_t* dgm = pgm + 10485760;                  // [2048][768] bf16
    ushort_t* wpreg_t = dgm + 1572864;               // [512][1280]
    ushort_t* wdreg_t = wpreg_t + 655360;            // [512][768]
    ushort_t* wqkvp_t = wdreg_t + 393216;            // [1536][512]
    ushort_t* wqkvd_t = wqkvp_t + 786432;            // [1536][512]
    ushort_t* pg = wqkvd_t + 786432;                 // [8192][512] bf16
    ushort_t* dg = pg + 4194304;                     // [2048][512] bf16
    _Float16* qkvp = (_Float16*)(dg + 1048576);      // [8192][1536] f16
    _Float16* qkvd = qkvp + 12582912;                // [2048][1536] f16
    _Float16* VT   = qkvd + 3145728;                 // [256][64][320] f16
    int* mg = (int*)(VT + 5242880);                  // [8192]
    int* md = mg + 8192;                             // [2048]
    // overlay: dgm dead after drug regression GEMM -> x / MLP tmps
    // region = 147456 floats << 786432-float dgm region
    float* x  = (float*)dgm;                         // [32][1024]
    float* s1 = x + 32768;                           // raw sums layer1 [32][1024]
    float* h1 = s1 + 32768;                          // bn out layer1
    float* s2 = h1 + 32768;                          // [32][512]
    float* h2 = s2 + 16384;
    float* s3 = h2 + 16384;                          // [32][256]
    float* h3 = s3 + 8192;

    // 1. group means (mean commutes with the linear regression layers) -> bf16
    group_mean_kernel<<<(BATCH * GP * DP / 4) / 256, 256, 0, stream>>>(prot_embed, pgm, DP / 4, BATCH * GP * DP / 4);
    group_mean_kernel<<<(BATCH * GD * DD / 4) / 256, 256, 0, stream>>>(drug_embed, dgm, DD / 4, BATCH * GD * DD / 4);
    group_mask_kernel<<<(BATCH * GP) / 256, 256, 0, stream>>>(prot_mask, mg, BATCH * GP);
    group_mask_kernel<<<(BATCH * GD) / 256, 256, 0, stream>>>(drug_mask, md, BATCH * GD);

    // 2. all 8 weight transposes in one launch
    TransJobs J;
    J.src[0] = w_preg; J.dst[0] = wpreg_t; J.K[0] = DP;  J.N[0] = HID;
    J.src[1] = w_dreg; J.dst[1] = wdreg_t; J.K[1] = DD;  J.N[1] = HID;
    J.src[2] = wqp; J.dst[2] = wqkvp_t;              J.K[2] = HID; J.N[2] = HID;
    J.src[3] = wkp; J.dst[3] = wqkvp_t + 512 * 512;  J.K[3] = HID; J.N[3] = HID;
    J.src[4] = wvp; J.dst[4] = wqkvp_t + 1024 * 512; J.K[4] = HID; J.N[4] = HID;
    J.src[5] = wqd; J.dst[5] = wqkvd_t;              J.K[5] = HID; J.N[5] = HID;
    J.src[6] = wkd; J.dst[6] = wqkvd_t + 512 * 512;  J.K[6] = HID; J.N[6] = HID;
    J.src[7] = wvd; J.dst[7] = wqkvd_t + 1024 * 512; J.K[7] = HID; J.N[7] = HID;
    {
        int base = 0;
        for (int i = 0; i < 8; ++i) { J.base[i] = base; base += (J.K[i] / 32) * (J.N[i] / 32); }
        transpose_cast8_kernel<<<base, 256, 0, stream>>>(J);
    }

    // 3. regression GEMMs (bf16 out, bias), then fused QKV GEMMs (f16 out + VT)
    mfma_gemm_kernel<<<dim3(HID / 128, (BATCH * GP) / 128), 256, 0, stream>>>(
        pgm, wpreg_t, b_preg, pg, BATCH * GP, HID, DP);
    mfma_gemm_kernel<<<dim3(HID / 128, (BATCH * GD) / 128), 256, 0, stream>>>(
        dgm, wdreg_t, b_dreg, dg, BATCH * GD, HID, DD);
    // dgm now dead -> zero x (attn accumulator) + s1..h3 (split-K sums)
    zero_scratch_kernel<<<576, 256, 0, stream>>>(x);
    qkv_gemm_kernel<GP, 0><<<dim3(1536 / 128, (BATCH * GP) / 128), 256, 0, stream>>>(
        pg, wqkvp_t, qkvp, VT);
    qkv_gemm_kernel<GD, GP><<<dim3(1536 / 128, (BATCH * GD) / 128), 256, 0, stream>>>(
        dg, wqkvd_t, qkvd, VT);

    // 4. fused attention (logits + segmented masked softmax + mix + pooled sums)
    fused_attn_kernel<<<dim3(5, BATCH * NH), 256, 0, stream>>>(qkvp, qkvd, VT, mg, md, x);

    // 5. masked-mean: divide pooled sums by counts
    pool_div_kernel<<<BATCH, 1024, 0, stream>>>(x, mg, md);

    // 6. MLP head: split-K block-tiled GEMM (atomic raw sums) + fused bias/ReLU/BN
    mlp_gemm_tiled<1024, 1024><<<dim3(BATCH, 1024 / 64, 4), 256, 0, stream>>>(x, w1, s1);
    bn_relu_kernel<1024><<<1024 / 64, 256, 0, stream>>>(s1, b1, g1, be1, h1);
    mlp_gemm_tiled<1024, 512><<<dim3(BATCH, 512 / 64, 4), 256, 0, stream>>>(h1, w2, s2);
    bn_relu_kernel<512><<<512 / 64, 256, 0, stream>>>(s2, b2, g2, be2, h2);
    mlp_gemm_tiled<512, 256><<<dim3(BATCH, 256 / 64, 4), 256, 0, stream>>>(h2, w3, s3);
    bn_relu_kernel<256><<<256 / 64, 256, 0, stream>>>(s3, b3, g3, be3, h3);
    final_kernel<<<BATCH, 64, 0, stream>>>(h3, wo, bo, (float*)d_out);
}